// Round 1
// baseline (241.050 us; speedup 1.0000x reference)
//
#include <hip/hip_runtime.h>
#include <cstdint>
#include <cstddef>

#define NB 32
#define NP 128
#define NR 16
#define ND 1024
#define RHOC 0.97f
#define EPSN 1e-8f

#define TM 64
#define TN 64
#define TK 16

// ---------------- K0: detect mask storage (uint8 vs int32) ----------------
// If mask is int32 (values 0/1), every byte at index%4!=0 is zero.
// If mask is uint8 bernoulli(0.05) over 4096 elems, ~146 of the 3072
// non-multiple-of-4 bytes are 1 (P(all zero) ~ e^-157). flag=1 -> uint8.
__global__ void detect_mask_kernel(const unsigned char* __restrict__ m,
                                   int* __restrict__ flag) {
  __shared__ int red[256];
  int tid = threadIdx.x;
  int v = 0;
  for (int i = tid; i < NB * NP; i += 256) {
    if ((i & 3) != 0 && m[i] != 0) v = 1;
  }
  red[tid] = v;
  __syncthreads();
  for (int off = 128; off > 0; off >>= 1) {
    if (tid < off) red[tid] |= red[tid + off];
    __syncthreads();
  }
  if (tid == 0) *flag = red[0];
}

// ---------------- K1: per-(b,t) scalars: c, A, csum ----------------
__global__ void scalars_kernel(const float* __restrict__ surprise,
                               const void* __restrict__ mask,
                               const int* __restrict__ flag,
                               float* __restrict__ c,
                               float* __restrict__ Abuf,
                               float* __restrict__ csum) {
  int b = blockIdx.x;
  int t = threadIdx.x;  // 128 threads
  __shared__ float a_sh[NP];
  __shared__ float suf[NP + 1];
  __shared__ float red[NP];
  float g = surprise[b * NP + t] * 0.2f;
  g = fminf(fmaxf(g, 0.f), 1.f);
  int mv;
  if (*flag) mv = ((const unsigned char*)mask)[b * NP + t];
  else       mv = ((const int*)mask)[b * NP + t];
  float a = RHOC * (mv ? 0.f : 1.f);
  a_sh[t] = a;
  __syncthreads();
  if (t == 0) {
    float p = 1.f;
    suf[NP] = 1.f;
    for (int s = NP - 1; s >= 0; --s) { p *= a_sh[s]; suf[s] = p; }
  }
  __syncthreads();
  float cv = g * suf[t + 1];
  c[b * NP + t] = cv;
  red[t] = cv;
  __syncthreads();
  for (int off = 64; off > 0; off >>= 1) {
    if (t < off) red[t] += red[t + off];
    __syncthreads();
  }
  if (t == 0) { csum[b] = red[0]; Abuf[b] = suf[0]; }
}

// ---------------- K2: hbar[b,d] = sum_t c[b,t]*h[b,t,d] ----------------
__global__ __launch_bounds__(256) void hbar_kernel(const float* __restrict__ h,
                                                   const float* __restrict__ c,
                                                   float* __restrict__ hbar) {
  int b = blockIdx.y;
  int d = blockIdx.x * 256 + threadIdx.x;
  __shared__ float cs[NP];
  if (threadIdx.x < NP) cs[threadIdx.x] = c[b * NP + threadIdx.x];
  __syncthreads();
  const float* hb = h + (size_t)b * NP * ND + d;
  float acc = 0.f;
#pragma unroll 8
  for (int t = 0; t < NP; ++t) acc += cs[t] * hb[(size_t)t * ND];
  hbar[b * ND + d] = acc;
}

// ------ K3: elig_V[b,r,d] = A*eV0 + (hbar[b,:]@Wv[:,d] + csum*bv[d]) ------
__global__ __launch_bounds__(256) void eligv_kernel(const float* __restrict__ hbar,
                                                    const float* __restrict__ Wv,
                                                    const float* __restrict__ bv,
                                                    const float* __restrict__ eV0,
                                                    const float* __restrict__ Abuf,
                                                    const float* __restrict__ csum,
                                                    float* __restrict__ outV) {
  int b = blockIdx.y;
  int d = blockIdx.x * 256 + threadIdx.x;
  __shared__ float hs[ND];
  for (int i = threadIdx.x; i < ND; i += 256) hs[i] = hbar[b * ND + i];
  __syncthreads();
  float acc = 0.f;
#pragma unroll 8
  for (int e = 0; e < ND; ++e) acc += hs[e] * Wv[(size_t)e * ND + d];
  acc += csum[b] * bv[d];
  float A = Abuf[b];
  for (int r = 0; r < NR; ++r) {
    size_t idx = ((size_t)(b * NR + r)) * ND + d;
    outV[idx] = A * eV0[idx] + acc;
  }
}

// ---------------- K4: kraw = x @ W_k + b_k (fp32 tiled GEMM) ----------------
__global__ __launch_bounds__(256) void kgemm_kernel(const float* __restrict__ X,
                                                    const float* __restrict__ W,
                                                    const float* __restrict__ bk,
                                                    float* __restrict__ out,
                                                    int row_base) {
  __shared__ float As[TK][TM + 4];
  __shared__ float Bs[TK][TN];
  int tid = threadIdx.x;
  int bn = blockIdx.x, bm = blockIdx.y;
  int grow0 = row_base + bm * TM;  // global X row
  int lrow0 = bm * TM;             // chunk-local out row
  int col0 = bn * TN;
  int tx = tid & 15, ty = tid >> 4;
  int arow = tid >> 2, acol = (tid & 3) * 4;
  int brow = tid >> 4, bcol = (tid & 15) * 4;
  float acc[4][4] = {};
  for (int k0 = 0; k0 < ND; k0 += TK) {
    float4 av = *(const float4*)&X[(size_t)(grow0 + arow) * ND + k0 + acol];
    float4 bvv = *(const float4*)&W[(size_t)(k0 + brow) * ND + col0 + bcol];
    As[acol + 0][arow] = av.x;
    As[acol + 1][arow] = av.y;
    As[acol + 2][arow] = av.z;
    As[acol + 3][arow] = av.w;
    *(float4*)&Bs[brow][bcol] = bvv;
    __syncthreads();
#pragma unroll
    for (int k = 0; k < TK; ++k) {
      float a[4], bb[4];
#pragma unroll
      for (int i = 0; i < 4; ++i) a[i] = As[k][ty * 4 + i];
#pragma unroll
      for (int j = 0; j < 4; ++j) bb[j] = Bs[k][tx * 4 + j];
#pragma unroll
      for (int i = 0; i < 4; ++i)
#pragma unroll
        for (int j = 0; j < 4; ++j) acc[i][j] += a[i] * bb[j];
    }
    __syncthreads();
  }
#pragma unroll
  for (int i = 0; i < 4; ++i) {
#pragma unroll
    for (int j = 0; j < 4; ++j) {
      int cc = col0 + tx * 4 + j;
      out[(size_t)(lrow0 + ty * 4 + i) * ND + cc] = acc[i][j] + bk[cc];
    }
  }
}

// ---------------- K5a: row norms of kraw ----------------
__global__ __launch_bounds__(256) void rownorm_kernel(const float* __restrict__ kraw,
                                                      float* __restrict__ norms) {
  int m = blockIdx.x;
  int tid = threadIdx.x;
  const float* row = kraw + (size_t)m * ND;
  float s = 0.f;
  for (int i = tid; i < ND; i += 256) {
    float v = row[i];
    s += v * v;
  }
#pragma unroll
  for (int off = 32; off > 0; off >>= 1) s += __shfl_xor(s, off);
  __shared__ float red[4];
  int wave = tid >> 6, lane = tid & 63;
  if (lane == 0) red[wave] = s;
  __syncthreads();
  if (tid == 0) norms[m] = sqrtf(red[0] + red[1] + red[2] + red[3]);
}

// ------ K5b: elig_K[b,r,d] = A*eK0 + sum_t (c/max(norm,eps))*kraw ------
__global__ __launch_bounds__(256) void eligk_kernel(const float* __restrict__ kraw,
                                                    const float* __restrict__ norms,
                                                    const float* __restrict__ c,
                                                    const float* __restrict__ Abuf,
                                                    const float* __restrict__ eK0,
                                                    float* __restrict__ outK,
                                                    int b_base) {
  int bl = blockIdx.y;  // chunk-local b
  int b = b_base + bl;
  int d = blockIdx.x * 256 + threadIdx.x;
  __shared__ float wsh[NP];
  if (threadIdx.x < NP) {
    float n = norms[bl * NP + threadIdx.x];
    wsh[threadIdx.x] = c[b * NP + threadIdx.x] / fmaxf(n, EPSN);
  }
  __syncthreads();
  const float* kb = kraw + ((size_t)bl * NP) * ND + d;
  float acc = 0.f;
#pragma unroll 8
  for (int t = 0; t < NP; ++t) acc += wsh[t] * kb[(size_t)t * ND];
  float A = Abuf[b];
  for (int r = 0; r < NR; ++r) {
    size_t idx = ((size_t)(b * NR + r)) * ND + d;
    outK[idx] = A * eK0[idx] + acc;
  }
}

// ---------------- K6: y_pm ----------------
__global__ __launch_bounds__(256) void ypm_kernel(const float* __restrict__ x,
                                                  const float* __restrict__ pmK,
                                                  const float* __restrict__ pmV,
                                                  const float* __restrict__ pma,
                                                  float* __restrict__ y) {
  int p = blockIdx.x, b = blockIdx.y;
  int tid = threadIdx.x;
  const float* xr = x + ((size_t)b * NP + p) * ND;
  float xv[4];
  float ssq = 0.f;
#pragma unroll
  for (int i = 0; i < 4; ++i) {
    float v = xr[tid + 256 * i];
    xv[i] = v;
    ssq += v * v;
  }
  float sc[NR];
#pragma unroll
  for (int r = 0; r < NR; ++r) {
    const float* kr = pmK + ((size_t)b * NR + r) * ND;
    float s = 0.f;
#pragma unroll
    for (int i = 0; i < 4; ++i) s += xv[i] * kr[tid + 256 * i];
    sc[r] = s;
  }
#pragma unroll
  for (int off = 32; off > 0; off >>= 1) {
    ssq += __shfl_xor(ssq, off);
#pragma unroll
    for (int r = 0; r < NR; ++r) sc[r] += __shfl_xor(sc[r], off);
  }
  __shared__ float red[4][NR + 1];
  int wave = tid >> 6, lane = tid & 63;
  if (lane == 0) {
    red[wave][0] = ssq;
    for (int r = 0; r < NR; ++r) red[wave][r + 1] = sc[r];
  }
  __syncthreads();
  float tot = red[0][0] + red[1][0] + red[2][0] + red[3][0];
  float inv = 1.f / fmaxf(sqrtf(tot), EPSN);
  float w[NR];
#pragma unroll
  for (int r = 0; r < NR; ++r)
    w[r] = pma[b * NR + r] *
           (red[0][r + 1] + red[1][r + 1] + red[2][r + 1] + red[3][r + 1]) * inv;
  float* yr = y + ((size_t)b * NP + p) * ND;
#pragma unroll
  for (int i = 0; i < 4; ++i) {
    int d = tid + 256 * i;
    float acc = 0.f;
#pragma unroll
    for (int r = 0; r < NR; ++r) acc += w[r] * pmV[((size_t)b * NR + r) * ND + d];
    yr[d] = acc;
  }
}

extern "C" void kernel_launch(void* const* d_in, const int* in_sizes, int n_in,
                              void* d_out, int out_size, void* d_ws, size_t ws_size,
                              hipStream_t stream) {
  (void)in_sizes; (void)n_in; (void)out_size;
  const float* x_all    = (const float*)d_in[0];
  const float* h_all    = (const float*)d_in[1];
  const float* surprise = (const float*)d_in[2];
  const void*  mask     = d_in[3];
  const float* pmK      = (const float*)d_in[4];
  const float* pmV      = (const float*)d_in[5];
  const float* pma      = (const float*)d_in[6];
  const float* eK0      = (const float*)d_in[7];
  const float* eV0      = (const float*)d_in[8];
  const float* Wk       = (const float*)d_in[9];
  const float* bk       = (const float*)d_in[10];
  const float* Wv       = (const float*)d_in[11];
  const float* bv       = (const float*)d_in[12];

  float* y    = (float*)d_out;
  float* outK = y + (size_t)NB * NP * ND;
  float* outV = outK + (size_t)NB * NR * ND;

  char* w = (char*)d_ws;
  int*   flag = (int*)w;   w += 256;
  float* c    = (float*)w; w += NB * NP * 4;  // 16 KB
  float* Abuf = (float*)w; w += 256;
  float* csum = (float*)w; w += 256;
  float* hbar = (float*)w; w += NB * ND * 4;  // 128 KB
  float* norms= (float*)w; w += NB * NP * 4;  // 16 KB
  size_t fixed = (size_t)(w - (char*)d_ws);
  float* kraw = (float*)w;
  size_t avail = ws_size > fixed ? ws_size - fixed : 0;
  size_t per_b = (size_t)NP * ND * 4;  // 512 KB per batch of kraw
  int nb_chunk = (int)(avail / per_b);
  if (nb_chunk > NB) nb_chunk = NB;
  if (nb_chunk < 1) nb_chunk = 1;

  detect_mask_kernel<<<1, 256, 0, stream>>>((const unsigned char*)mask, flag);
  scalars_kernel<<<NB, NP, 0, stream>>>(surprise, mask, flag, c, Abuf, csum);
  hbar_kernel<<<dim3(ND / 256, NB), 256, 0, stream>>>(h_all, c, hbar);
  eligv_kernel<<<dim3(ND / 256, NB), 256, 0, stream>>>(hbar, Wv, bv, eV0, Abuf, csum, outV);
  ypm_kernel<<<dim3(NP, NB), 256, 0, stream>>>(x_all, pmK, pmV, pma, y);

  for (int b0 = 0; b0 < NB; b0 += nb_chunk) {
    int nb = (NB - b0 < nb_chunk) ? (NB - b0) : nb_chunk;
    kgemm_kernel<<<dim3(ND / TN, nb * NP / TM), 256, 0, stream>>>(x_all, Wk, bk, kraw, b0 * NP);
    rownorm_kernel<<<nb * NP, 256, 0, stream>>>(kraw, norms);
    eligk_kernel<<<dim3(ND / 256, nb), 256, 0, stream>>>(kraw, norms, c, Abuf, eK0, outK, b0);
  }
}

// Round 2
// 124.810 us; speedup vs baseline: 1.9313x; 1.9313x over previous
//
#include <hip/hip_runtime.h>
#include <cstdint>
#include <cstddef>

#define NB 32
#define NP 128
#define NR 16
#define ND 1024
#define RHOC 0.97f
#define EPSN 1e-8f

typedef short bf16x8 __attribute__((ext_vector_type(8)));
typedef float f32x4 __attribute__((ext_vector_type(4)));
typedef unsigned short ushort_t;

__device__ inline ushort_t f2bf(float f) {
  unsigned u = __float_as_uint(f);
  unsigned r = (u + 0x7fffu + ((u >> 16) & 1u)) >> 16;
  return (ushort_t)r;
}
__device__ inline float bf2f(ushort_t v) {
  return __uint_as_float(((unsigned)v) << 16);
}
__device__ inline void gload16(const void* g, void* l) {
  __builtin_amdgcn_global_load_lds(
      (const __attribute__((address_space(1))) void*)g,
      (__attribute__((address_space(3))) void*)l, 16, 0, 0);
}

// ---------------- K1: per-(b,t) scalars: c, A, csum (+mask dtype detect) ----
__global__ void scalars_kernel(const float* __restrict__ surprise,
                               const void* __restrict__ mask,
                               float* __restrict__ c,
                               float* __restrict__ Abuf,
                               float* __restrict__ csum) {
  int b = blockIdx.x;
  int t = threadIdx.x;  // 128 threads
  __shared__ float a_sh[NP];
  __shared__ float suf[NP + 1];
  __shared__ float red[NP];
  __shared__ int isu8;
  if (t == 0) isu8 = 0;
  __syncthreads();
  // detect: int32 storage has all bytes at idx%4!=0 equal to zero
  const unsigned char* mb = (const unsigned char*)mask;
  int v = 0;
  for (int i = t; i < NB * NP; i += NP) {
    if ((i & 3) != 0 && mb[i] != 0) v = 1;
  }
  if (v) isu8 = 1;
  __syncthreads();
  float g = surprise[b * NP + t] * 0.2f;
  g = fminf(fmaxf(g, 0.f), 1.f);
  int mv;
  if (isu8) mv = mb[b * NP + t];
  else      mv = ((const int*)mask)[b * NP + t];
  float a = RHOC * (mv ? 0.f : 1.f);
  a_sh[t] = a;
  __syncthreads();
  if (t == 0) {
    float p = 1.f;
    suf[NP] = 1.f;
    for (int s = NP - 1; s >= 0; --s) { p *= a_sh[s]; suf[s] = p; }
  }
  __syncthreads();
  float cv = g * suf[t + 1];
  c[b * NP + t] = cv;
  red[t] = cv;
  __syncthreads();
  for (int off = 64; off > 0; off >>= 1) {
    if (t < off) red[t] += red[t + off];
    __syncthreads();
  }
  if (t == 0) { csum[b] = red[0]; Abuf[b] = suf[0]; }
}

// ------- K2: hbar2[z][b][d] = sum_{t in half z} c[b,t]*h[b,t,d] -----------
__global__ __launch_bounds__(256) void hbar_kernel(const float* __restrict__ h,
                                                   const float* __restrict__ c,
                                                   float* __restrict__ hbar2) {
  int b = blockIdx.y, z = blockIdx.z;
  int d = blockIdx.x * 256 + threadIdx.x;
  __shared__ float cs[64];
  if (threadIdx.x < 64) cs[threadIdx.x] = c[b * NP + z * 64 + threadIdx.x];
  __syncthreads();
  const float* hb = h + ((size_t)b * NP + z * 64) * ND + d;
  float acc = 0.f;
#pragma unroll 16
  for (int t = 0; t < 64; ++t) acc += cs[t] * hb[(size_t)t * ND];
  hbar2[((size_t)z * NB + b) * ND + d] = acc;
}

// ------ K3: elig_V[b,r,d] = A*eV0 + (hbar[b,:]@Wv[:,d] + csum*bv[d]) ------
__global__ __launch_bounds__(256) void eligv_kernel(const float* __restrict__ hbar2,
                                                    const float* __restrict__ Wv,
                                                    const float* __restrict__ bv,
                                                    const float* __restrict__ eV0,
                                                    const float* __restrict__ Abuf,
                                                    const float* __restrict__ csum,
                                                    float* __restrict__ outV) {
  int b = blockIdx.y;
  int d = blockIdx.x * 256 + threadIdx.x;
  __shared__ float hs[ND];
  for (int i = threadIdx.x; i < ND; i += 256)
    hs[i] = hbar2[(size_t)b * ND + i] + hbar2[(size_t)(NB + b) * ND + i];
  __syncthreads();
  float acc = 0.f;
#pragma unroll 16
  for (int e = 0; e < ND; ++e) acc += hs[e] * Wv[(size_t)e * ND + d];
  acc += csum[b] * bv[d];
  float A = Abuf[b];
  for (int r = 0; r < NR; ++r) {
    size_t idx = ((size_t)(b * NR + r)) * ND + d;
    outV[idx] = A * eV0[idx] + acc;
  }
}

// ---------------- K4a: convert Wk -> bf16 transposed [N][K] ----------------
__global__ __launch_bounds__(256) void convwt_kernel(const float* __restrict__ W,
                                                     ushort_t* __restrict__ WT) {
  __shared__ ushort_t t[64][65];
  int tid = threadIdx.x;
  int k0 = blockIdx.y * 64, n0 = blockIdx.x * 64;
#pragma unroll
  for (int i = 0; i < 16; ++i) {
    int r = i * 4 + (tid >> 6), cc = tid & 63;
    t[r][cc] = f2bf(W[(size_t)(k0 + r) * ND + n0 + cc]);
  }
  __syncthreads();
#pragma unroll
  for (int i = 0; i < 16; ++i) {
    int r = i * 4 + (tid >> 6), cc = tid & 63;
    WT[(size_t)(n0 + r) * ND + k0 + cc] = t[cc][r];
  }
}

// ---------------- K4b: convert x -> bf16 (same layout) ---------------------
__global__ __launch_bounds__(256) void convx_kernel(const float* __restrict__ X,
                                                    ushort_t* __restrict__ Xb) {
  typedef unsigned short u16x8 __attribute__((ext_vector_type(8)));
  size_t i = (size_t)blockIdx.x * 256 + threadIdx.x;  // one per 8 elems
  const float4* p = (const float4*)(X + i * 8);
  float4 a = p[0], b = p[1];
  u16x8 o;
  o[0] = f2bf(a.x); o[1] = f2bf(a.y); o[2] = f2bf(a.z); o[3] = f2bf(a.w);
  o[4] = f2bf(b.x); o[5] = f2bf(b.y); o[6] = f2bf(b.z); o[7] = f2bf(b.w);
  *(u16x8*)(Xb + i * 8) = o;
}

// -------- K5: kraw = x @ W_k + b_k via bf16 MFMA; fused row-ssq ------------
// tile 128x128, BK=64, 4 waves (2x2), wave-tile 64x64 (4x4 frags of 16x16).
__global__ __launch_bounds__(256) void kgemm_mfma(const ushort_t* __restrict__ Xb,
                                                  const ushort_t* __restrict__ WT,
                                                  const float* __restrict__ bk,
                                                  ushort_t* __restrict__ kout,
                                                  float* __restrict__ norms2,
                                                  int row_base) {
  __shared__ ushort_t As[128 * 64];  // [row][slot(16B)] swizzled
  __shared__ ushort_t Bs[128 * 64];
  int tid = threadIdx.x;
  int lane = tid & 63, wid = tid >> 6;
  int wr = wid >> 1, wc = wid & 1;
  int bm = blockIdx.x, bn = blockIdx.y;  // m-major: 8 n-blocks of a row-panel
                                         // share one XCD (id%8 == bm%8)
  int m0 = bm * 128;                     // chunk-local out row
  int grow0 = row_base + m0;             // global X row
  int n0 = bn * 128;
  int lo = lane & 15, hi = lane >> 4;

  f32x4 acc[4][4] = {};

  for (int k0 = 0; k0 < ND; k0 += 64) {
#pragma unroll
    for (int i = 0; i < 4; ++i) {
      int sl = i * 256 + tid;
      int r = sl >> 3, s = sl & 7;
      int gk = k0 + ((s ^ (r & 7)) << 3);
      gload16(&Xb[(size_t)(grow0 + r) * ND + gk], &As[sl << 3]);
    }
#pragma unroll
    for (int i = 0; i < 4; ++i) {
      int sl = i * 256 + tid;
      int r = sl >> 3, s = sl & 7;
      int gk = k0 + ((s ^ (r & 7)) << 3);
      gload16(&WT[(size_t)(n0 + r) * ND + gk], &Bs[sl << 3]);
    }
    __syncthreads();
#pragma unroll
    for (int ksl = 0; ksl < 2; ++ksl) {
      bf16x8 af[4], bfr[4];
#pragma unroll
      for (int mi = 0; mi < 4; ++mi) {
        int r = wr * 64 + mi * 16 + lo;
        int cchunk = ksl * 4 + hi;
        int s = cchunk ^ (r & 7);
        af[mi] = *(const bf16x8*)&As[(r << 6) + (s << 3)];
      }
#pragma unroll
      for (int ni = 0; ni < 4; ++ni) {
        int r = wc * 64 + ni * 16 + lo;
        int cchunk = ksl * 4 + hi;
        int s = cchunk ^ (r & 7);
        bfr[ni] = *(const bf16x8*)&Bs[(r << 6) + (s << 3)];
      }
#pragma unroll
      for (int mi = 0; mi < 4; ++mi)
#pragma unroll
        for (int ni = 0; ni < 4; ++ni)
          acc[mi][ni] = __builtin_amdgcn_mfma_f32_16x16x32_bf16(
              af[mi], bfr[ni], acc[mi][ni], 0, 0, 0);
    }
    __syncthreads();
  }

  // epilogue: bias, bf16 store, fused per-row sum-of-squares
  float bkv[4];
#pragma unroll
  for (int ni = 0; ni < 4; ++ni) bkv[ni] = bk[n0 + wc * 64 + ni * 16 + lo];
#pragma unroll
  for (int mi = 0; mi < 4; ++mi) {
#pragma unroll
    for (int j = 0; j < 4; ++j) {
      int row = m0 + wr * 64 + mi * 16 + hi * 4 + j;
      float ss = 0.f;
#pragma unroll
      for (int ni = 0; ni < 4; ++ni) {
        int col = n0 + wc * 64 + ni * 16 + lo;
        float v = acc[mi][ni][j] + bkv[ni];
        kout[(size_t)row * ND + col] = f2bf(v);
        ss += v * v;
      }
      ss += __shfl_xor(ss, 1);
      ss += __shfl_xor(ss, 2);
      ss += __shfl_xor(ss, 4);
      ss += __shfl_xor(ss, 8);
      if (lo == 0) atomicAdd(&norms2[row_base + row], ss);
    }
  }
}

// ------ K6: elig_K[b,r,d] = A*eK0 + sum_t (c/max(norm,eps))*kraw -----------
__global__ __launch_bounds__(256) void eligk_kernel(const ushort_t* __restrict__ kraw,
                                                    const float* __restrict__ norms2,
                                                    const float* __restrict__ c,
                                                    const float* __restrict__ Abuf,
                                                    const float* __restrict__ eK0,
                                                    float* __restrict__ outK,
                                                    int b_base) {
  int bl = blockIdx.y;  // chunk-local b
  int b = b_base + bl;
  int d = blockIdx.x * 256 + threadIdx.x;
  __shared__ float wsh[NP];
  if (threadIdx.x < NP) {
    float n = sqrtf(norms2[b * NP + threadIdx.x]);
    wsh[threadIdx.x] = c[b * NP + threadIdx.x] / fmaxf(n, EPSN);
  }
  __syncthreads();
  const ushort_t* kb = kraw + ((size_t)bl * NP) * ND + d;
  float acc = 0.f;
#pragma unroll 16
  for (int t = 0; t < NP; ++t) acc += wsh[t] * bf2f(kb[(size_t)t * ND]);
  float A = Abuf[b];
  for (int r = 0; r < NR; ++r) {
    size_t idx = ((size_t)(b * NR + r)) * ND + d;
    outK[idx] = A * eK0[idx] + acc;
  }
}

// ---------------- K7: y_pm ----------------
__global__ __launch_bounds__(256) void ypm_kernel(const float* __restrict__ x,
                                                  const float* __restrict__ pmK,
                                                  const float* __restrict__ pmV,
                                                  const float* __restrict__ pma,
                                                  float* __restrict__ y) {
  int p = blockIdx.x, b = blockIdx.y;
  int tid = threadIdx.x;
  const float* xr = x + ((size_t)b * NP + p) * ND;
  float xv[4];
  float ssq = 0.f;
#pragma unroll
  for (int i = 0; i < 4; ++i) {
    float v = xr[tid + 256 * i];
    xv[i] = v;
    ssq += v * v;
  }
  float sc[NR];
#pragma unroll
  for (int r = 0; r < NR; ++r) {
    const float* kr = pmK + ((size_t)b * NR + r) * ND;
    float s = 0.f;
#pragma unroll
    for (int i = 0; i < 4; ++i) s += xv[i] * kr[tid + 256 * i];
    sc[r] = s;
  }
#pragma unroll
  for (int off = 32; off > 0; off >>= 1) {
    ssq += __shfl_xor(ssq, off);
#pragma unroll
    for (int r = 0; r < NR; ++r) sc[r] += __shfl_xor(sc[r], off);
  }
  __shared__ float red[4][NR + 1];
  int wave = tid >> 6, lane = tid & 63;
  if (lane == 0) {
    red[wave][0] = ssq;
    for (int r = 0; r < NR; ++r) red[wave][r + 1] = sc[r];
  }
  __syncthreads();
  float tot = red[0][0] + red[1][0] + red[2][0] + red[3][0];
  float inv = 1.f / fmaxf(sqrtf(tot), EPSN);
  float w[NR];
#pragma unroll
  for (int r = 0; r < NR; ++r)
    w[r] = pma[b * NR + r] *
           (red[0][r + 1] + red[1][r + 1] + red[2][r + 1] + red[3][r + 1]) * inv;
  float* yr = y + ((size_t)b * NP + p) * ND;
#pragma unroll
  for (int i = 0; i < 4; ++i) {
    int d = tid + 256 * i;
    float acc = 0.f;
#pragma unroll
    for (int r = 0; r < NR; ++r) acc += w[r] * pmV[((size_t)b * NR + r) * ND + d];
    yr[d] = acc;
  }
}

extern "C" void kernel_launch(void* const* d_in, const int* in_sizes, int n_in,
                              void* d_out, int out_size, void* d_ws, size_t ws_size,
                              hipStream_t stream) {
  (void)in_sizes; (void)n_in; (void)out_size;
  const float* x_all    = (const float*)d_in[0];
  const float* h_all    = (const float*)d_in[1];
  const float* surprise = (const float*)d_in[2];
  const void*  mask     = d_in[3];
  const float* pmK      = (const float*)d_in[4];
  const float* pmV      = (const float*)d_in[5];
  const float* pma      = (const float*)d_in[6];
  const float* eK0      = (const float*)d_in[7];
  const float* eV0      = (const float*)d_in[8];
  const float* Wk       = (const float*)d_in[9];
  const float* bk       = (const float*)d_in[10];
  const float* Wv       = (const float*)d_in[11];
  const float* bv       = (const float*)d_in[12];

  float* y    = (float*)d_out;
  float* outK = y + (size_t)NB * NP * ND;
  float* outV = outK + (size_t)NB * NR * ND;

  char* w = (char*)d_ws;
  float* c      = (float*)w; w += NB * NP * 4;            // 16 KB
  float* Abuf   = (float*)w; w += 256;
  float* csum   = (float*)w; w += 256;
  float* hbar2  = (float*)w; w += 2 * NB * ND * 4;        // 256 KB
  float* norms2 = (float*)w; w += NB * NP * 4;            // 16 KB
  ushort_t* WkT = (ushort_t*)w; w += (size_t)ND * ND * 2; // 2 MB
  ushort_t* Xb  = (ushort_t*)w; w += (size_t)NB * NP * ND * 2;  // 8 MB
  size_t fixed = (size_t)(w - (char*)d_ws);
  ushort_t* kraw = (ushort_t*)w;
  size_t avail = ws_size > fixed ? ws_size - fixed : 0;
  size_t per_b = (size_t)NP * ND * 2;  // 256 KB per batch of kraw (bf16)
  int nb_chunk = (int)(avail / per_b);
  if (nb_chunk > NB) nb_chunk = NB;
  if (nb_chunk < 1) nb_chunk = 1;

  hipMemsetAsync(norms2, 0, NB * NP * 4, stream);
  scalars_kernel<<<NB, NP, 0, stream>>>(surprise, mask, c, Abuf, csum);
  hbar_kernel<<<dim3(ND / 256, NB, 2), 256, 0, stream>>>(h_all, c, hbar2);
  eligv_kernel<<<dim3(ND / 256, NB), 256, 0, stream>>>(hbar2, Wv, bv, eV0, Abuf, csum, outV);
  ypm_kernel<<<dim3(NP, NB), 256, 0, stream>>>(x_all, pmK, pmV, pma, y);
  convwt_kernel<<<dim3(ND / 64, ND / 64), 256, 0, stream>>>(Wk, WkT);
  convx_kernel<<<(NB * NP * ND / 8) / 256, 256, 0, stream>>>(x_all, Xb);

  for (int b0 = 0; b0 < NB; b0 += nb_chunk) {
    int nb = (NB - b0 < nb_chunk) ? (NB - b0) : nb_chunk;
    kgemm_mfma<<<dim3(nb, ND / 128), 256, 0, stream>>>(Xb, WkT, bk, kraw, norms2, b0 * NP);
    eligk_kernel<<<dim3(ND / 256, nb), 256, 0, stream>>>(kraw, norms2, c, Abuf, eK0, outK, b0);
  }
}

// Round 3
// 96.874 us; speedup vs baseline: 2.4883x; 1.2884x over previous
//
#include <hip/hip_runtime.h>
#include <cstdint>
#include <cstddef>

#define NB 32
#define NP 128
#define NR 16
#define ND 1024
#define RHOC 0.97f
#define EPSN 1e-8f

typedef short bf16x8 __attribute__((ext_vector_type(8)));
typedef float f32x4 __attribute__((ext_vector_type(4)));
typedef unsigned short ushort_t;

__device__ inline ushort_t f2bf(float f) {
  unsigned u = __float_as_uint(f);
  unsigned r = (u + 0x7fffu + ((u >> 16) & 1u)) >> 16;
  return (ushort_t)r;
}
__device__ inline float bf2f(ushort_t v) {
  return __uint_as_float(((unsigned)v) << 16);
}
__device__ inline void gload16(const void* g, void* l) {
  __builtin_amdgcn_global_load_lds(
      (const __attribute__((address_space(1))) void*)g,
      (__attribute__((address_space(3))) void*)l, 16, 0, 0);
}

// ---------------- K1: per-(b,t) scalars: c, A, csum (+mask dtype detect) ----
__global__ void scalars_kernel(const float* __restrict__ surprise,
                               const void* __restrict__ mask,
                               float* __restrict__ c,
                               float* __restrict__ Abuf,
                               float* __restrict__ csum) {
  int b = blockIdx.x;
  int t = threadIdx.x;  // 128 threads
  __shared__ float a_sh[NP];
  __shared__ float suf[NP + 1];
  __shared__ float red[NP];
  __shared__ int isu8;
  if (t == 0) isu8 = 0;
  __syncthreads();
  // detect: int32 storage has all bytes at idx%4!=0 equal to zero
  const unsigned char* mb = (const unsigned char*)mask;
  int v = 0;
  for (int i = t; i < NB * NP; i += NP) {
    if ((i & 3) != 0 && mb[i] != 0) v = 1;
  }
  if (v) isu8 = 1;
  __syncthreads();
  float g = surprise[b * NP + t] * 0.2f;
  g = fminf(fmaxf(g, 0.f), 1.f);
  int mv;
  if (isu8) mv = mb[b * NP + t];
  else      mv = ((const int*)mask)[b * NP + t];
  float a = RHOC * (mv ? 0.f : 1.f);
  a_sh[t] = a;
  __syncthreads();
  if (t == 0) {
    float p = 1.f;
    suf[NP] = 1.f;
    for (int s = NP - 1; s >= 0; --s) { p *= a_sh[s]; suf[s] = p; }
  }
  __syncthreads();
  float cv = g * suf[t + 1];
  c[b * NP + t] = cv;
  red[t] = cv;
  __syncthreads();
  for (int off = 64; off > 0; off >>= 1) {
    if (t < off) red[t] += red[t + off];
    __syncthreads();
  }
  if (t == 0) { csum[b] = red[0]; Abuf[b] = suf[0]; }
}

// ------- K2: hbar[b][d] = sum_t c[b,t]*h[b,t,d]  (full-t in one block) -----
__global__ __launch_bounds__(256) void hbar_kernel(const float* __restrict__ h,
                                                   const float* __restrict__ c,
                                                   float* __restrict__ hbar) {
  int b = blockIdx.y;
  int dd = threadIdx.x & 63, sl = threadIdx.x >> 6;
  int d = blockIdx.x * 64 + dd;
  __shared__ float cs[NP];
  __shared__ float red[4][64];
  if (threadIdx.x < NP) cs[threadIdx.x] = c[b * NP + threadIdx.x];
  __syncthreads();
  const float* hb = h + ((size_t)b * NP + sl * 32) * ND + d;
  float acc = 0.f;
#pragma unroll
  for (int t = 0; t < 32; ++t) acc += cs[sl * 32 + t] * hb[(size_t)t * ND];
  red[sl][dd] = acc;
  __syncthreads();
  if (sl == 0)
    hbar[(size_t)b * ND + d] = red[0][dd] + red[1][dd] + red[2][dd] + red[3][dd];
}

// ------- K3a: vpart[gsl][b][d] = sum_{e in slice} hbar[b,e]*Wv[e,d] --------
// grid (16 dchunks, 16 echunks), 256 thr = 64 d x 4 slices of 16 e
__global__ __launch_bounds__(256) void vpart_kernel(const float* __restrict__ hbar,
                                                    const float* __restrict__ Wv,
                                                    float* __restrict__ vpart) {
  int dd = threadIdx.x & 63, sl = threadIdx.x >> 6;
  int d = blockIdx.x * 64 + dd;
  int e0 = blockIdx.y * 64;
  __shared__ float hs[32][64];
  for (int i = threadIdx.x; i < 32 * 64; i += 256) {
    int bb = i >> 6, el = i & 63;
    hs[bb][el] = hbar[(size_t)bb * ND + e0 + el];
  }
  __syncthreads();
  float acc[32] = {};
#pragma unroll
  for (int ei = 0; ei < 16; ++ei) {
    int el = sl * 16 + ei;
    float w = Wv[(size_t)(e0 + el) * ND + d];
#pragma unroll
    for (int b = 0; b < 32; ++b) acc[b] += hs[b][el] * w;
  }
  int gsl = blockIdx.y * 4 + sl;  // 0..63
#pragma unroll
  for (int b = 0; b < 32; ++b)
    vpart[((size_t)gsl * 32 + b) * ND + d] = acc[b];
}

// ------- K3b: elig_V[b,r,d] = A*eV0 + (sum_gsl vpart + csum*bv[d]) ---------
__global__ __launch_bounds__(256) void eligv_combine(const float* __restrict__ vpart,
                                                     const float* __restrict__ bv,
                                                     const float* __restrict__ eV0,
                                                     const float* __restrict__ Abuf,
                                                     const float* __restrict__ csum,
                                                     float* __restrict__ outV) {
  int b = blockIdx.y;
  int d = blockIdx.x * 256 + threadIdx.x;
  float acc = 0.f;
#pragma unroll
  for (int s = 0; s < 64; ++s) acc += vpart[((size_t)s * 32 + b) * ND + d];
  acc += csum[b] * bv[d];
  float A = Abuf[b];
#pragma unroll
  for (int r = 0; r < NR; ++r) {
    size_t idx = ((size_t)(b * NR + r)) * ND + d;
    outV[idx] = A * eV0[idx] + acc;
  }
}

// ------- K3-fallback: old single-kernel eligv (if ws too small) ------------
__global__ __launch_bounds__(256) void eligv_fallback(const float* __restrict__ hbar,
                                                      const float* __restrict__ Wv,
                                                      const float* __restrict__ bv,
                                                      const float* __restrict__ eV0,
                                                      const float* __restrict__ Abuf,
                                                      const float* __restrict__ csum,
                                                      float* __restrict__ outV) {
  int b = blockIdx.y;
  int d = blockIdx.x * 256 + threadIdx.x;
  __shared__ float hs[ND];
  for (int i = threadIdx.x; i < ND; i += 256) hs[i] = hbar[(size_t)b * ND + i];
  __syncthreads();
  float acc = 0.f;
#pragma unroll 16
  for (int e = 0; e < ND; ++e) acc += hs[e] * Wv[(size_t)e * ND + d];
  acc += csum[b] * bv[d];
  float A = Abuf[b];
  for (int r = 0; r < NR; ++r) {
    size_t idx = ((size_t)(b * NR + r)) * ND + d;
    outV[idx] = A * eV0[idx] + acc;
  }
}

// ---------------- K4a: convert Wk -> bf16 transposed [N][K] ----------------
__global__ __launch_bounds__(256) void convwt_kernel(const float* __restrict__ W,
                                                     ushort_t* __restrict__ WT) {
  __shared__ ushort_t t[64][65];
  int tid = threadIdx.x;
  int k0 = blockIdx.y * 64, n0 = blockIdx.x * 64;
#pragma unroll
  for (int i = 0; i < 16; ++i) {
    int r = i * 4 + (tid >> 6), cc = tid & 63;
    t[r][cc] = f2bf(W[(size_t)(k0 + r) * ND + n0 + cc]);
  }
  __syncthreads();
#pragma unroll
  for (int i = 0; i < 16; ++i) {
    int r = i * 4 + (tid >> 6), cc = tid & 63;
    WT[(size_t)(n0 + r) * ND + k0 + cc] = t[cc][r];
  }
}

// -------- K5: kraw = x @ W_k + b_k via bf16 MFMA; fused row-ssq ------------
// tile 128x128, BK=64, 4 waves (2x2), wave-tile 64x64 (4x4 frags of 16x16).
__global__ __launch_bounds__(256) void kgemm_mfma(const ushort_t* __restrict__ Xb,
                                                  const ushort_t* __restrict__ WT,
                                                  const float* __restrict__ bk,
                                                  ushort_t* __restrict__ kout,
                                                  float* __restrict__ norms2,
                                                  int row_base) {
  __shared__ ushort_t As[128 * 64];  // [row][slot(16B)] swizzled
  __shared__ ushort_t Bs[128 * 64];
  int tid = threadIdx.x;
  int lane = tid & 63, wid = tid >> 6;
  int wr = wid >> 1, wc = wid & 1;
  int bm = blockIdx.x, bn = blockIdx.y;  // m-major: 8 n-blocks of a row-panel
  int m0 = bm * 128;                     // chunk-local out row
  int grow0 = row_base + m0;             // global X row
  int n0 = bn * 128;
  int lo = lane & 15, hi = lane >> 4;

  f32x4 acc[4][4] = {};

  for (int k0 = 0; k0 < ND; k0 += 64) {
#pragma unroll
    for (int i = 0; i < 4; ++i) {
      int sl = i * 256 + tid;
      int r = sl >> 3, s = sl & 7;
      int gk = k0 + ((s ^ (r & 7)) << 3);
      gload16(&Xb[(size_t)(grow0 + r) * ND + gk], &As[sl << 3]);
    }
#pragma unroll
    for (int i = 0; i < 4; ++i) {
      int sl = i * 256 + tid;
      int r = sl >> 3, s = sl & 7;
      int gk = k0 + ((s ^ (r & 7)) << 3);
      gload16(&WT[(size_t)(n0 + r) * ND + gk], &Bs[sl << 3]);
    }
    __syncthreads();
#pragma unroll
    for (int ksl = 0; ksl < 2; ++ksl) {
      bf16x8 af[4], bfr[4];
#pragma unroll
      for (int mi = 0; mi < 4; ++mi) {
        int r = wr * 64 + mi * 16 + lo;
        int cchunk = ksl * 4 + hi;
        int s = cchunk ^ (r & 7);
        af[mi] = *(const bf16x8*)&As[(r << 6) + (s << 3)];
      }
#pragma unroll
      for (int ni = 0; ni < 4; ++ni) {
        int r = wc * 64 + ni * 16 + lo;
        int cchunk = ksl * 4 + hi;
        int s = cchunk ^ (r & 7);
        bfr[ni] = *(const bf16x8*)&Bs[(r << 6) + (s << 3)];
      }
#pragma unroll
      for (int mi = 0; mi < 4; ++mi)
#pragma unroll
        for (int ni = 0; ni < 4; ++ni)
          acc[mi][ni] = __builtin_amdgcn_mfma_f32_16x16x32_bf16(
              af[mi], bfr[ni], acc[mi][ni], 0, 0, 0);
    }
    __syncthreads();
  }

  // epilogue: bias, bf16 store, fused per-row sum-of-squares
  float bkv[4];
#pragma unroll
  for (int ni = 0; ni < 4; ++ni) bkv[ni] = bk[n0 + wc * 64 + ni * 16 + lo];
#pragma unroll
  for (int mi = 0; mi < 4; ++mi) {
#pragma unroll
    for (int j = 0; j < 4; ++j) {
      int row = m0 + wr * 64 + mi * 16 + hi * 4 + j;
      float ss = 0.f;
#pragma unroll
      for (int ni = 0; ni < 4; ++ni) {
        int col = n0 + wc * 64 + ni * 16 + lo;
        float v = acc[mi][ni][j] + bkv[ni];
        kout[(size_t)row * ND + col] = f2bf(v);
        ss += v * v;
      }
      ss += __shfl_xor(ss, 1);
      ss += __shfl_xor(ss, 2);
      ss += __shfl_xor(ss, 4);
      ss += __shfl_xor(ss, 8);
      if (lo == 0) atomicAdd(&norms2[row_base + row], ss);
    }
  }
}

// ------ K6: elig_K[b,r,d] = A*eK0 + sum_t (c/max(norm,eps))*kraw -----------
// grid (8, nb), 256 thr = 64 d-pairs x 4 t-slices of 32
__global__ __launch_bounds__(256) void eligk_kernel(const ushort_t* __restrict__ kraw,
                                                    const float* __restrict__ norms2,
                                                    const float* __restrict__ c,
                                                    const float* __restrict__ Abuf,
                                                    const float* __restrict__ eK0,
                                                    float* __restrict__ outK,
                                                    int b_base) {
  int bl = blockIdx.y;  // chunk-local b
  int b = b_base + bl;
  int dd = threadIdx.x & 63, sl = threadIdx.x >> 6;
  int d = blockIdx.x * 128 + dd * 2;
  __shared__ float wsh[NP];
  __shared__ float red[4][64][2];
  if (threadIdx.x < NP) {
    float n = sqrtf(norms2[b * NP + threadIdx.x]);
    wsh[threadIdx.x] = c[b * NP + threadIdx.x] / fmaxf(n, EPSN);
  }
  __syncthreads();
  const ushort_t* kb = kraw + ((size_t)bl * NP + sl * 32) * ND + d;
  float ax = 0.f, ay = 0.f;
#pragma unroll
  for (int t = 0; t < 32; ++t) {
    unsigned u = *(const unsigned*)&kb[(size_t)t * ND];
    float w = wsh[sl * 32 + t];
    ax += w * bf2f((ushort_t)(u & 0xffffu));
    ay += w * bf2f((ushort_t)(u >> 16));
  }
  red[sl][dd][0] = ax;
  red[sl][dd][1] = ay;
  __syncthreads();
  if (sl == 0) {
    float sx = red[0][dd][0] + red[1][dd][0] + red[2][dd][0] + red[3][dd][0];
    float sy = red[0][dd][1] + red[1][dd][1] + red[2][dd][1] + red[3][dd][1];
    float A = Abuf[b];
#pragma unroll
    for (int r = 0; r < NR; ++r) {
      size_t idx = ((size_t)(b * NR + r)) * ND + d;
      float2 e = *(const float2*)&eK0[idx];
      float2 o;
      o.x = A * e.x + sx;
      o.y = A * e.y + sy;
      *(float2*)&outK[idx] = o;
    }
  }
}

// ---------------- K7: y_pm (+ fused x->bf16 conversion) ----------------
__global__ __launch_bounds__(256) void ypm_kernel(const float* __restrict__ x,
                                                  const float* __restrict__ pmK,
                                                  const float* __restrict__ pmV,
                                                  const float* __restrict__ pma,
                                                  float* __restrict__ y,
                                                  ushort_t* __restrict__ Xb) {
  int p = blockIdx.x, b = blockIdx.y;
  int tid = threadIdx.x;
  const float* xr = x + ((size_t)b * NP + p) * ND;
  float xv[4];
  float ssq = 0.f;
#pragma unroll
  for (int i = 0; i < 4; ++i) {
    float v = xr[tid + 256 * i];
    xv[i] = v;
    ssq += v * v;
  }
  // fused convx
  ushort_t* xbr = Xb + ((size_t)b * NP + p) * ND;
#pragma unroll
  for (int i = 0; i < 4; ++i) xbr[tid + 256 * i] = f2bf(xv[i]);
  float sc[NR];
#pragma unroll
  for (int r = 0; r < NR; ++r) {
    const float* kr = pmK + ((size_t)b * NR + r) * ND;
    float s = 0.f;
#pragma unroll
    for (int i = 0; i < 4; ++i) s += xv[i] * kr[tid + 256 * i];
    sc[r] = s;
  }
#pragma unroll
  for (int off = 32; off > 0; off >>= 1) {
    ssq += __shfl_xor(ssq, off);
#pragma unroll
    for (int r = 0; r < NR; ++r) sc[r] += __shfl_xor(sc[r], off);
  }
  __shared__ float red[4][NR + 1];
  int wave = tid >> 6, lane = tid & 63;
  if (lane == 0) {
    red[wave][0] = ssq;
    for (int r = 0; r < NR; ++r) red[wave][r + 1] = sc[r];
  }
  __syncthreads();
  float tot = red[0][0] + red[1][0] + red[2][0] + red[3][0];
  float inv = 1.f / fmaxf(sqrtf(tot), EPSN);
  float w[NR];
#pragma unroll
  for (int r = 0; r < NR; ++r)
    w[r] = pma[b * NR + r] *
           (red[0][r + 1] + red[1][r + 1] + red[2][r + 1] + red[3][r + 1]) * inv;
  float* yr = y + ((size_t)b * NP + p) * ND;
#pragma unroll
  for (int i = 0; i < 4; ++i) {
    int d = tid + 256 * i;
    float acc = 0.f;
#pragma unroll
    for (int r = 0; r < NR; ++r) acc += w[r] * pmV[((size_t)b * NR + r) * ND + d];
    yr[d] = acc;
  }
}

extern "C" void kernel_launch(void* const* d_in, const int* in_sizes, int n_in,
                              void* d_out, int out_size, void* d_ws, size_t ws_size,
                              hipStream_t stream) {
  (void)in_sizes; (void)n_in; (void)out_size;
  const float* x_all    = (const float*)d_in[0];
  const float* h_all    = (const float*)d_in[1];
  const float* surprise = (const float*)d_in[2];
  const void*  mask     = d_in[3];
  const float* pmK      = (const float*)d_in[4];
  const float* pmV      = (const float*)d_in[5];
  const float* pma      = (const float*)d_in[6];
  const float* eK0      = (const float*)d_in[7];
  const float* eV0      = (const float*)d_in[8];
  const float* Wk       = (const float*)d_in[9];
  const float* bk       = (const float*)d_in[10];
  const float* Wv       = (const float*)d_in[11];
  const float* bv       = (const float*)d_in[12];

  float* y    = (float*)d_out;
  float* outK = y + (size_t)NB * NP * ND;
  float* outV = outK + (size_t)NB * NR * ND;

  char* w = (char*)d_ws;
  float* c      = (float*)w; w += NB * NP * 4;            // 16 KB
  float* Abuf   = (float*)w; w += 256;
  float* csum   = (float*)w; w += 256;
  float* hbar   = (float*)w; w += NB * ND * 4;            // 128 KB
  float* norms2 = (float*)w; w += NB * NP * 4;            // 16 KB
  ushort_t* WkT = (ushort_t*)w; w += (size_t)ND * ND * 2; // 2 MB
  ushort_t* Xb  = (ushort_t*)w; w += (size_t)NB * NP * ND * 2;  // 8 MB
  size_t fixed = (size_t)(w - (char*)d_ws);
  // scratch region S: vpart (8 MB) then reused by kraw (disjoint lifetimes)
  float* vpart = (float*)w;
  ushort_t* kraw = (ushort_t*)w;
  size_t avail = ws_size > fixed ? ws_size - fixed : 0;
  size_t vpart_need = (size_t)64 * NB * ND * 4;  // 8 MB
  int use_vpart = (avail >= vpart_need) ? 1 : 0;
  size_t per_b = (size_t)NP * ND * 2;  // 256 KB per batch of kraw (bf16)
  int nb_chunk = (int)(avail / per_b);
  if (nb_chunk > NB) nb_chunk = NB;
  if (nb_chunk < 1) nb_chunk = 1;

  hipMemsetAsync(norms2, 0, NB * NP * 4, stream);
  scalars_kernel<<<NB, NP, 0, stream>>>(surprise, mask, c, Abuf, csum);
  hbar_kernel<<<dim3(ND / 64, NB), 256, 0, stream>>>(h_all, c, hbar);
  if (use_vpart) {
    vpart_kernel<<<dim3(ND / 64, 16), 256, 0, stream>>>(hbar, Wv, vpart);
    eligv_combine<<<dim3(ND / 256, NB), 256, 0, stream>>>(vpart, bv, eV0, Abuf, csum, outV);
  } else {
    eligv_fallback<<<dim3(ND / 256, NB), 256, 0, stream>>>(hbar, Wv, bv, eV0, Abuf, csum, outV);
  }
  ypm_kernel<<<dim3(NP, NB), 256, 0, stream>>>(x_all, pmK, pmV, pma, y, Xb);
  convwt_kernel<<<dim3(ND / 64, ND / 64), 256, 0, stream>>>(Wk, WkT);

  for (int b0 = 0; b0 < NB; b0 += nb_chunk) {
    int nb = (NB - b0 < nb_chunk) ? (NB - b0) : nb_chunk;
    kgemm_mfma<<<dim3(nb, ND / 128), 256, 0, stream>>>(Xb, WkT, bk, kraw, norms2, b0 * NP);
    eligk_kernel<<<dim3(ND / 128, nb), 256, 0, stream>>>(kraw, norms2, c, Abuf, eK0, outK, b0);
  }
}

// Round 4
// 95.336 us; speedup vs baseline: 2.5284x; 1.0161x over previous
//
#include <hip/hip_runtime.h>
#include <cstdint>
#include <cstddef>

#define NB 32
#define NP 128
#define NR 16
#define ND 1024
#define RHOC 0.97f
#define EPSN 1e-8f

typedef short bf16x8 __attribute__((ext_vector_type(8)));
typedef float f32x4 __attribute__((ext_vector_type(4)));
typedef unsigned short ushort_t;

__device__ inline ushort_t f2bf(float f) {
  unsigned u = __float_as_uint(f);
  unsigned r = (u + 0x7fffu + ((u >> 16) & 1u)) >> 16;
  return (ushort_t)r;
}
__device__ inline float bf2f(ushort_t v) {
  return __uint_as_float(((unsigned)v) << 16);
}
__device__ inline void gload16(const void* g, void* l) {
  __builtin_amdgcn_global_load_lds(
      (const __attribute__((address_space(1))) void*)g,
      (__attribute__((address_space(3))) void*)l, 16, 0, 0);
}

// ---------------- K1: per-(b,t) scalars: c, A, csum (+mask dtype detect) ----
__global__ void scalars_kernel(const float* __restrict__ surprise,
                               const void* __restrict__ mask,
                               float* __restrict__ c,
                               float* __restrict__ Abuf,
                               float* __restrict__ csum) {
  int b = blockIdx.x;
  int t = threadIdx.x;  // 128 threads
  __shared__ float a_sh[NP];
  __shared__ float suf[NP + 1];
  __shared__ float red[NP];
  __shared__ int isu8;
  if (t == 0) isu8 = 0;
  __syncthreads();
  // detect: int32 storage has all bytes at idx%4!=0 equal to zero
  const unsigned char* mb = (const unsigned char*)mask;
  int v = 0;
  for (int i = t; i < NB * NP; i += NP) {
    if ((i & 3) != 0 && mb[i] != 0) v = 1;
  }
  if (v) isu8 = 1;
  __syncthreads();
  float g = surprise[b * NP + t] * 0.2f;
  g = fminf(fmaxf(g, 0.f), 1.f);
  int mv;
  if (isu8) mv = mb[b * NP + t];
  else      mv = ((const int*)mask)[b * NP + t];
  float a = RHOC * (mv ? 0.f : 1.f);
  a_sh[t] = a;
  __syncthreads();
  if (t == 0) {
    float p = 1.f;
    suf[NP] = 1.f;
    for (int s = NP - 1; s >= 0; --s) { p *= a_sh[s]; suf[s] = p; }
  }
  __syncthreads();
  float cv = g * suf[t + 1];
  c[b * NP + t] = cv;
  red[t] = cv;
  __syncthreads();
  for (int off = 64; off > 0; off >>= 1) {
    if (t < off) red[t] += red[t + off];
    __syncthreads();
  }
  if (t == 0) { csum[b] = red[0]; Abuf[b] = suf[0]; }
}

// ------- K2: hbar[b][d] = sum_t c[b,t]*h[b,t,d]  (full-t in one block) -----
__global__ __launch_bounds__(256) void hbar_kernel(const float* __restrict__ h,
                                                   const float* __restrict__ c,
                                                   float* __restrict__ hbar) {
  int b = blockIdx.y;
  int dd = threadIdx.x & 63, sl = threadIdx.x >> 6;
  int d = blockIdx.x * 64 + dd;
  __shared__ float cs[NP];
  __shared__ float red[4][64];
  if (threadIdx.x < NP) cs[threadIdx.x] = c[b * NP + threadIdx.x];
  __syncthreads();
  const float* hb = h + ((size_t)b * NP + sl * 32) * ND + d;
  float acc = 0.f;
#pragma unroll
  for (int t = 0; t < 32; ++t) acc += cs[sl * 32 + t] * hb[(size_t)t * ND];
  red[sl][dd] = acc;
  __syncthreads();
  if (sl == 0)
    hbar[(size_t)b * ND + d] = red[0][dd] + red[1][dd] + red[2][dd] + red[3][dd];
}

// ------- K3: elig_V fused: grid (16 dchunks, 16 bpairs), 256 thr -----------
// thread = (dd 0..63, esl 0..3); per-block 2 b's; Wv is L3-resident.
__global__ __launch_bounds__(256) void eligv_kernel(const float* __restrict__ hbar,
                                                    const float* __restrict__ Wv,
                                                    const float* __restrict__ bv,
                                                    const float* __restrict__ eV0,
                                                    const float* __restrict__ Abuf,
                                                    const float* __restrict__ csum,
                                                    float* __restrict__ outV) {
  int dd = threadIdx.x & 63, esl = threadIdx.x >> 6;
  int d = blockIdx.x * 64 + dd;
  int b0 = blockIdx.y * 2;
  __shared__ float hs[2][ND];
  __shared__ float red[4][2][64];
  for (int i = threadIdx.x; i < 2 * ND; i += 256) {
    int bb = i >> 10, e = i & 1023;
    hs[bb][e] = hbar[(size_t)(b0 + bb) * ND + e];
  }
  __syncthreads();
  float a0 = 0.f, a1 = 0.f;
  const float* wcol = Wv + d;
#pragma unroll 8
  for (int ei = 0; ei < 256; ++ei) {
    int e = esl * 256 + ei;
    float w = wcol[(size_t)e * ND];
    a0 += hs[0][e] * w;
    a1 += hs[1][e] * w;
  }
  red[esl][0][dd] = a0;
  red[esl][1][dd] = a1;
  __syncthreads();
  if (threadIdx.x < 128) {
    int bb = threadIdx.x >> 6, ddd = threadIdx.x & 63;
    int b = b0 + bb;
    int dg = blockIdx.x * 64 + ddd;
    float s = red[0][bb][ddd] + red[1][bb][ddd] + red[2][bb][ddd] + red[3][bb][ddd];
    s += csum[b] * bv[dg];
    float A = Abuf[b];
#pragma unroll
    for (int r = 0; r < NR; ++r) {
      size_t idx = ((size_t)(b * NR + r)) * ND + dg;
      outV[idx] = A * eV0[idx] + s;
    }
  }
}

// ---------------- K4: convert Wk -> bf16 transposed [N][K] ----------------
__global__ __launch_bounds__(256) void convwt_kernel(const float* __restrict__ W,
                                                     ushort_t* __restrict__ WT) {
  __shared__ ushort_t t[64][65];
  int tid = threadIdx.x;
  int k0 = blockIdx.y * 64, n0 = blockIdx.x * 64;
#pragma unroll
  for (int i = 0; i < 16; ++i) {
    int r = i * 4 + (tid >> 6), cc = tid & 63;
    t[r][cc] = f2bf(W[(size_t)(k0 + r) * ND + n0 + cc]);
  }
  __syncthreads();
#pragma unroll
  for (int i = 0; i < 16; ++i) {
    int r = i * 4 + (tid >> 6), cc = tid & 63;
    WT[(size_t)(n0 + r) * ND + k0 + cc] = t[cc][r];
  }
}

// -------- K5: kraw = x @ W_k + b_k via bf16 MFMA (8 waves); ssq partials ---
// tile 128x128, BK=64, 8 waves (2x4), wave-tile 64x32 (4x2 frags of 16x16).
__global__ __launch_bounds__(512) void kgemm_mfma(const ushort_t* __restrict__ Xb,
                                                  const ushort_t* __restrict__ WT,
                                                  const float* __restrict__ bk,
                                                  ushort_t* __restrict__ kout,
                                                  float* __restrict__ norms2p,
                                                  int row_base) {
  __shared__ ushort_t As[128 * 64];  // [row][slot(16B)] swizzled
  __shared__ ushort_t Bs[128 * 64];
  int tid = threadIdx.x;
  int lane = tid & 63, wid = tid >> 6;
  int wr = wid >> 2, wc = wid & 3;       // 2 x 4 wave grid
  int bm = blockIdx.x, bn = blockIdx.y;  // gridDim.x = 32 -> bm%8 fixes XCD;
                                         // same-bm blocks across bn share A in L2
  int m0 = bm * 128;                     // chunk-local out row
  int grow0 = row_base + m0;             // global X row
  int n0 = bn * 128;
  int lo = lane & 15, hi = lane >> 4;

  f32x4 acc[4][2] = {};

  for (int k0 = 0; k0 < ND; k0 += 64) {
#pragma unroll
    for (int i = 0; i < 2; ++i) {
      int sl = i * 512 + tid;
      int r = sl >> 3, s = sl & 7;
      int gk = k0 + ((s ^ (r & 7)) << 3);
      gload16(&Xb[(size_t)(grow0 + r) * ND + gk], &As[sl << 3]);
    }
#pragma unroll
    for (int i = 0; i < 2; ++i) {
      int sl = i * 512 + tid;
      int r = sl >> 3, s = sl & 7;
      int gk = k0 + ((s ^ (r & 7)) << 3);
      gload16(&WT[(size_t)(n0 + r) * ND + gk], &Bs[sl << 3]);
    }
    __syncthreads();
#pragma unroll
    for (int ksl = 0; ksl < 2; ++ksl) {
      bf16x8 af[4], bfr[2];
#pragma unroll
      for (int mi = 0; mi < 4; ++mi) {
        int r = wr * 64 + mi * 16 + lo;
        int cchunk = ksl * 4 + hi;
        int s = cchunk ^ (r & 7);
        af[mi] = *(const bf16x8*)&As[(r << 6) + (s << 3)];
      }
#pragma unroll
      for (int ni = 0; ni < 2; ++ni) {
        int r = wc * 32 + ni * 16 + lo;
        int cchunk = ksl * 4 + hi;
        int s = cchunk ^ (r & 7);
        bfr[ni] = *(const bf16x8*)&Bs[(r << 6) + (s << 3)];
      }
#pragma unroll
      for (int mi = 0; mi < 4; ++mi)
#pragma unroll
        for (int ni = 0; ni < 2; ++ni)
          acc[mi][ni] = __builtin_amdgcn_mfma_f32_16x16x32_bf16(
              af[mi], bfr[ni], acc[mi][ni], 0, 0, 0);
    }
    __syncthreads();
  }

  // epilogue: bias, bf16 store, ssq partial per (bn,wc) 32-col span
  float bkv[2];
#pragma unroll
  for (int ni = 0; ni < 2; ++ni) bkv[ni] = bk[n0 + wc * 32 + ni * 16 + lo];
  int pc = bn * 4 + wc;  // 0..31
#pragma unroll
  for (int mi = 0; mi < 4; ++mi) {
#pragma unroll
    for (int j = 0; j < 4; ++j) {
      int row = m0 + wr * 64 + mi * 16 + hi * 4 + j;
      float ss = 0.f;
#pragma unroll
      for (int ni = 0; ni < 2; ++ni) {
        int col = n0 + wc * 32 + ni * 16 + lo;
        float v = acc[mi][ni][j] + bkv[ni];
        kout[(size_t)row * ND + col] = f2bf(v);
        ss += v * v;
      }
      ss += __shfl_xor(ss, 1);
      ss += __shfl_xor(ss, 2);
      ss += __shfl_xor(ss, 4);
      ss += __shfl_xor(ss, 8);
      if (lo == 0) norms2p[(size_t)pc * (NB * NP) + row_base + row] = ss;
    }
  }
}

// ------ K6: elig_K[b,r,d] = A*eK0 + sum_t (c/max(norm,eps))*kraw -----------
// grid (8, nb), 256 thr = 64 d-pairs x 4 t-slices of 32
__global__ __launch_bounds__(256) void eligk_kernel(const ushort_t* __restrict__ kraw,
                                                    const float* __restrict__ norms2p,
                                                    const float* __restrict__ c,
                                                    const float* __restrict__ Abuf,
                                                    const float* __restrict__ eK0,
                                                    float* __restrict__ outK,
                                                    int b_base) {
  int bl = blockIdx.y;  // chunk-local b
  int b = b_base + bl;
  int dd = threadIdx.x & 63, sl = threadIdx.x >> 6;
  int d = blockIdx.x * 128 + dd * 2;
  __shared__ float wsh[NP];
  __shared__ float red[4][64][2];
  if (threadIdx.x < NP) {
    float s = 0.f;
#pragma unroll
    for (int pc = 0; pc < 32; ++pc)
      s += norms2p[(size_t)pc * (NB * NP) + b * NP + threadIdx.x];
    float n = sqrtf(s);
    wsh[threadIdx.x] = c[b * NP + threadIdx.x] / fmaxf(n, EPSN);
  }
  __syncthreads();
  const ushort_t* kb = kraw + ((size_t)bl * NP + sl * 32) * ND + d;
  float ax = 0.f, ay = 0.f;
#pragma unroll
  for (int t = 0; t < 32; ++t) {
    unsigned u = *(const unsigned*)&kb[(size_t)t * ND];
    float w = wsh[sl * 32 + t];
    ax += w * bf2f((ushort_t)(u & 0xffffu));
    ay += w * bf2f((ushort_t)(u >> 16));
  }
  red[sl][dd][0] = ax;
  red[sl][dd][1] = ay;
  __syncthreads();
  if (sl == 0) {
    float sx = red[0][dd][0] + red[1][dd][0] + red[2][dd][0] + red[3][dd][0];
    float sy = red[0][dd][1] + red[1][dd][1] + red[2][dd][1] + red[3][dd][1];
    float A = Abuf[b];
#pragma unroll
    for (int r = 0; r < NR; ++r) {
      size_t idx = ((size_t)(b * NR + r)) * ND + d;
      float2 e = *(const float2*)&eK0[idx];
      float2 o;
      o.x = A * e.x + sx;
      o.y = A * e.y + sy;
      *(float2*)&outK[idx] = o;
    }
  }
}

// ---------------- K7: y_pm (+ fused x->bf16 conversion) ----------------
__global__ __launch_bounds__(256) void ypm_kernel(const float* __restrict__ x,
                                                  const float* __restrict__ pmK,
                                                  const float* __restrict__ pmV,
                                                  const float* __restrict__ pma,
                                                  float* __restrict__ y,
                                                  ushort_t* __restrict__ Xb) {
  int p = blockIdx.x, b = blockIdx.y;
  int tid = threadIdx.x;
  const float* xr = x + ((size_t)b * NP + p) * ND;
  float xv[4];
  float ssq = 0.f;
#pragma unroll
  for (int i = 0; i < 4; ++i) {
    float v = xr[tid + 256 * i];
    xv[i] = v;
    ssq += v * v;
  }
  // fused convx
  ushort_t* xbr = Xb + ((size_t)b * NP + p) * ND;
#pragma unroll
  for (int i = 0; i < 4; ++i) xbr[tid + 256 * i] = f2bf(xv[i]);
  float sc[NR];
#pragma unroll
  for (int r = 0; r < NR; ++r) {
    const float* kr = pmK + ((size_t)b * NR + r) * ND;
    float s = 0.f;
#pragma unroll
    for (int i = 0; i < 4; ++i) s += xv[i] * kr[tid + 256 * i];
    sc[r] = s;
  }
#pragma unroll
  for (int off = 32; off > 0; off >>= 1) {
    ssq += __shfl_xor(ssq, off);
#pragma unroll
    for (int r = 0; r < NR; ++r) sc[r] += __shfl_xor(sc[r], off);
  }
  __shared__ float red[4][NR + 1];
  int wave = tid >> 6, lane = tid & 63;
  if (lane == 0) {
    red[wave][0] = ssq;
    for (int r = 0; r < NR; ++r) red[wave][r + 1] = sc[r];
  }
  __syncthreads();
  float tot = red[0][0] + red[1][0] + red[2][0] + red[3][0];
  float inv = 1.f / fmaxf(sqrtf(tot), EPSN);
  float w[NR];
#pragma unroll
  for (int r = 0; r < NR; ++r)
    w[r] = pma[b * NR + r] *
           (red[0][r + 1] + red[1][r + 1] + red[2][r + 1] + red[3][r + 1]) * inv;
  float* yr = y + ((size_t)b * NP + p) * ND;
#pragma unroll
  for (int i = 0; i < 4; ++i) {
    int d = tid + 256 * i;
    float acc = 0.f;
#pragma unroll
    for (int r = 0; r < NR; ++r) acc += w[r] * pmV[((size_t)b * NR + r) * ND + d];
    yr[d] = acc;
  }
}

extern "C" void kernel_launch(void* const* d_in, const int* in_sizes, int n_in,
                              void* d_out, int out_size, void* d_ws, size_t ws_size,
                              hipStream_t stream) {
  (void)in_sizes; (void)n_in; (void)out_size;
  const float* x_all    = (const float*)d_in[0];
  const float* h_all    = (const float*)d_in[1];
  const float* surprise = (const float*)d_in[2];
  const void*  mask     = d_in[3];
  const float* pmK      = (const float*)d_in[4];
  const float* pmV      = (const float*)d_in[5];
  const float* pma      = (const float*)d_in[6];
  const float* eK0      = (const float*)d_in[7];
  const float* eV0      = (const float*)d_in[8];
  const float* Wk       = (const float*)d_in[9];
  const float* bk       = (const float*)d_in[10];
  const float* Wv       = (const float*)d_in[11];
  const float* bv       = (const float*)d_in[12];

  float* y    = (float*)d_out;
  float* outK = y + (size_t)NB * NP * ND;
  float* outV = outK + (size_t)NB * NR * ND;

  char* w = (char*)d_ws;
  float* c       = (float*)w; w += NB * NP * 4;             // 16 KB
  float* Abuf    = (float*)w; w += 256;
  float* csum    = (float*)w; w += 256;
  float* hbar    = (float*)w; w += NB * ND * 4;             // 128 KB
  float* norms2p = (float*)w; w += (size_t)32 * NB * NP * 4;  // 512 KB
  ushort_t* WkT  = (ushort_t*)w; w += (size_t)ND * ND * 2;  // 2 MB
  ushort_t* Xb   = (ushort_t*)w; w += (size_t)NB * NP * ND * 2;  // 8 MB
  size_t fixed = (size_t)(w - (char*)d_ws);
  ushort_t* kraw = (ushort_t*)w;
  size_t avail = ws_size > fixed ? ws_size - fixed : 0;
  size_t per_b = (size_t)NP * ND * 2;  // 256 KB per batch of kraw (bf16)
  int nb_chunk = (int)(avail / per_b);
  if (nb_chunk > NB) nb_chunk = NB;
  if (nb_chunk < 1) nb_chunk = 1;

  scalars_kernel<<<NB, NP, 0, stream>>>(surprise, mask, c, Abuf, csum);
  hbar_kernel<<<dim3(ND / 64, NB), 256, 0, stream>>>(h_all, c, hbar);
  ypm_kernel<<<dim3(NP, NB), 256, 0, stream>>>(x_all, pmK, pmV, pma, y, Xb);
  convwt_kernel<<<dim3(ND / 64, ND / 64), 256, 0, stream>>>(Wk, WkT);
  eligv_kernel<<<dim3(ND / 64, NB / 2), 256, 0, stream>>>(hbar, Wv, bv, eV0, Abuf, csum, outV);

  for (int b0 = 0; b0 < NB; b0 += nb_chunk) {
    int nb = (NB - b0 < nb_chunk) ? (NB - b0) : nb_chunk;
    kgemm_mfma<<<dim3(nb, ND / 128), 512, 0, stream>>>(Xb, WkT, bk, kraw, norms2p, b0 * NP);
    eligk_kernel<<<dim3(ND / 128, nb), 256, 0, stream>>>(kraw, norms2p, c, Abuf, eK0, outK, b0);
  }
}

// Round 5
// 93.454 us; speedup vs baseline: 2.5793x; 1.0201x over previous
//
#include <hip/hip_runtime.h>
#include <cstdint>
#include <cstddef>

#define NB 32
#define NP 128
#define NR 16
#define ND 1024
#define RHOC 0.97f
#define EPSN 1e-8f

typedef short bf16x8 __attribute__((ext_vector_type(8)));
typedef float f32x4 __attribute__((ext_vector_type(4)));
typedef unsigned short ushort_t;

__device__ inline ushort_t f2bf(float f) {
  unsigned u = __float_as_uint(f);
  unsigned r = (u + 0x7fffu + ((u >> 16) & 1u)) >> 16;
  return (ushort_t)r;
}
__device__ inline float bf2f(ushort_t v) {
  return __uint_as_float(((unsigned)v) << 16);
}
__device__ inline void gload16(const void* g, void* l) {
  __builtin_amdgcn_global_load_lds(
      (const __attribute__((address_space(1))) void*)g,
      (__attribute__((address_space(3))) void*)l, 16, 0, 0);
}

// ---------------- K1: per-(b,t) scalars: c, A, csum (+mask dtype detect) ----
__global__ void scalars_kernel(const float* __restrict__ surprise,
                               const void* __restrict__ mask,
                               float* __restrict__ c,
                               float* __restrict__ Abuf,
                               float* __restrict__ csum) {
  int b = blockIdx.x;
  int t = threadIdx.x;  // 128 threads
  __shared__ float a_sh[NP];
  __shared__ float suf[NP + 1];
  __shared__ float red[NP];
  __shared__ int isu8;
  if (t == 0) isu8 = 0;
  __syncthreads();
  // detect: int32 storage has all bytes at idx%4!=0 equal to zero
  const unsigned char* mb = (const unsigned char*)mask;
  int v = 0;
  for (int i = t; i < NB * NP; i += NP) {
    if ((i & 3) != 0 && mb[i] != 0) v = 1;
  }
  if (v) isu8 = 1;
  __syncthreads();
  float g = surprise[b * NP + t] * 0.2f;
  g = fminf(fmaxf(g, 0.f), 1.f);
  int mv;
  if (isu8) mv = mb[b * NP + t];
  else      mv = ((const int*)mask)[b * NP + t];
  float a = RHOC * (mv ? 0.f : 1.f);
  a_sh[t] = a;
  __syncthreads();
  if (t == 0) {
    float p = 1.f;
    suf[NP] = 1.f;
    for (int s = NP - 1; s >= 0; --s) { p *= a_sh[s]; suf[s] = p; }
  }
  __syncthreads();
  float cv = g * suf[t + 1];
  c[b * NP + t] = cv;
  red[t] = cv;
  __syncthreads();
  for (int off = 64; off > 0; off >>= 1) {
    if (t < off) red[t] += red[t + off];
    __syncthreads();
  }
  if (t == 0) { csum[b] = red[0]; Abuf[b] = suf[0]; }
}

// ------- K2: hbar[b][d] = sum_t c[b,t]*h[b,t,d]  (full-t in one block) -----
__global__ __launch_bounds__(256) void hbar_kernel(const float* __restrict__ h,
                                                   const float* __restrict__ c,
                                                   float* __restrict__ hbar) {
  int b = blockIdx.y;
  int dd = threadIdx.x & 63, sl = threadIdx.x >> 6;
  int d = blockIdx.x * 64 + dd;
  __shared__ float cs[NP];
  __shared__ float red[4][64];
  if (threadIdx.x < NP) cs[threadIdx.x] = c[b * NP + threadIdx.x];
  __syncthreads();
  const float* hb = h + ((size_t)b * NP + sl * 32) * ND + d;
  float acc = 0.f;
#pragma unroll
  for (int t = 0; t < 32; ++t) acc += cs[sl * 32 + t] * hb[(size_t)t * ND];
  red[sl][dd] = acc;
  __syncthreads();
  if (sl == 0)
    hbar[(size_t)b * ND + d] = red[0][dd] + red[1][dd] + red[2][dd] + red[3][dd];
}

// ---------------- K3: convert Wk -> bf16 transposed [N][K] ----------------
__global__ __launch_bounds__(256) void convwt_kernel(const float* __restrict__ W,
                                                     ushort_t* __restrict__ WT) {
  __shared__ ushort_t t[64][65];
  int tid = threadIdx.x;
  int k0 = blockIdx.y * 64, n0 = blockIdx.x * 64;
#pragma unroll
  for (int i = 0; i < 16; ++i) {
    int r = i * 4 + (tid >> 6), cc = tid & 63;
    t[r][cc] = f2bf(W[(size_t)(k0 + r) * ND + n0 + cc]);
  }
  __syncthreads();
#pragma unroll
  for (int i = 0; i < 16; ++i) {
    int r = i * 4 + (tid >> 6), cc = tid & 63;
    WT[(size_t)(n0 + r) * ND + k0 + cc] = t[cc][r];
  }
}

// -------- K4: row norms^2 of (x @ W_k + b_k) via bf16 MFMA (no kraw store) -
// tile 128x128, BK=64, 8 waves (2x4), wave-tile 64x32 (4x2 frags of 16x16).
// Output: norms2p[bn][row] = partial ssq over this block's 128-col span.
__global__ __launch_bounds__(512) void kgemm_norms(const ushort_t* __restrict__ Xb,
                                                   const ushort_t* __restrict__ WT,
                                                   const float* __restrict__ bk,
                                                   float* __restrict__ norms2p) {
  __shared__ ushort_t As[128 * 64];  // [row][slot(16B)] swizzled
  __shared__ ushort_t Bs[128 * 64];
  __shared__ float sred[4][128];
  int tid = threadIdx.x;
  int lane = tid & 63, wid = tid >> 6;
  int wr = wid >> 2, wc = wid & 3;       // 2 x 4 wave grid
  int bm = blockIdx.x, bn = blockIdx.y;  // x fastest: bm%8 fixes XCD (A reuse)
  int m0 = bm * 128;
  int n0 = bn * 128;
  int lo = lane & 15, hi = lane >> 4;

  f32x4 acc[4][2] = {};

  for (int k0 = 0; k0 < ND; k0 += 64) {
#pragma unroll
    for (int i = 0; i < 2; ++i) {
      int sl = i * 512 + tid;
      int r = sl >> 3, s = sl & 7;
      int gk = k0 + ((s ^ (r & 7)) << 3);
      gload16(&Xb[(size_t)(m0 + r) * ND + gk], &As[sl << 3]);
    }
#pragma unroll
    for (int i = 0; i < 2; ++i) {
      int sl = i * 512 + tid;
      int r = sl >> 3, s = sl & 7;
      int gk = k0 + ((s ^ (r & 7)) << 3);
      gload16(&WT[(size_t)(n0 + r) * ND + gk], &Bs[sl << 3]);
    }
    __syncthreads();
#pragma unroll
    for (int ksl = 0; ksl < 2; ++ksl) {
      bf16x8 af[4], bfr[2];
#pragma unroll
      for (int mi = 0; mi < 4; ++mi) {
        int r = wr * 64 + mi * 16 + lo;
        int cchunk = ksl * 4 + hi;
        int s = cchunk ^ (r & 7);
        af[mi] = *(const bf16x8*)&As[(r << 6) + (s << 3)];
      }
#pragma unroll
      for (int ni = 0; ni < 2; ++ni) {
        int r = wc * 32 + ni * 16 + lo;
        int cchunk = ksl * 4 + hi;
        int s = cchunk ^ (r & 7);
        bfr[ni] = *(const bf16x8*)&Bs[(r << 6) + (s << 3)];
      }
#pragma unroll
      for (int mi = 0; mi < 4; ++mi)
#pragma unroll
        for (int ni = 0; ni < 2; ++ni)
          acc[mi][ni] = __builtin_amdgcn_mfma_f32_16x16x32_bf16(
              af[mi], bfr[ni], acc[mi][ni], 0, 0, 0);
    }
    __syncthreads();
  }

  // epilogue: bias + per-row partial ssq over this wave's 32-col span
  float bkv[2];
#pragma unroll
  for (int ni = 0; ni < 2; ++ni) bkv[ni] = bk[n0 + wc * 32 + ni * 16 + lo];
#pragma unroll
  for (int mi = 0; mi < 4; ++mi) {
#pragma unroll
    for (int j = 0; j < 4; ++j) {
      float ss = 0.f;
#pragma unroll
      for (int ni = 0; ni < 2; ++ni) {
        float v = acc[mi][ni][j] + bkv[ni];
        ss += v * v;
      }
      ss += __shfl_xor(ss, 1);
      ss += __shfl_xor(ss, 2);
      ss += __shfl_xor(ss, 4);
      ss += __shfl_xor(ss, 8);
      if (lo == 0) sred[wc][wr * 64 + mi * 16 + hi * 4 + j] = ss;
    }
  }
  __syncthreads();
  if (tid < 128)
    norms2p[(size_t)bn * (NB * NP) + m0 + tid] =
        sred[0][tid] + sred[1][tid] + sred[2][tid] + sred[3][tid];
}

// ------ K5: wsh = c/max(norm,eps); xbar[b,d] = sum_t wsh*x_bf16; wsum ------
// grid (8 dchunks, 32 b), 256 thr = 64 d-pairs x 4 t-slices of 32
__global__ __launch_bounds__(256) void xbarw_kernel(const ushort_t* __restrict__ Xb,
                                                    const float* __restrict__ norms2p,
                                                    const float* __restrict__ c,
                                                    float* __restrict__ xbar,
                                                    float* __restrict__ wsum) {
  int b = blockIdx.y;
  int dd = threadIdx.x & 63, sl = threadIdx.x >> 6;
  int d = blockIdx.x * 128 + dd * 2;
  __shared__ float wsh[NP];
  __shared__ float red[4][64][2];
  if (threadIdx.x < NP) {
    float s = 0.f;
#pragma unroll
    for (int bn = 0; bn < 8; ++bn)
      s += norms2p[(size_t)bn * (NB * NP) + b * NP + threadIdx.x];
    wsh[threadIdx.x] = c[b * NP + threadIdx.x] / fmaxf(sqrtf(s), EPSN);
  }
  __syncthreads();
  if (blockIdx.x == 0 && threadIdx.x == 0) {
    float s = 0.f;
    for (int t = 0; t < NP; ++t) s += wsh[t];
    wsum[b] = s;
  }
  const ushort_t* xb = Xb + ((size_t)b * NP + sl * 32) * ND + d;
  float ax = 0.f, ay = 0.f;
#pragma unroll
  for (int t = 0; t < 32; ++t) {
    unsigned u = *(const unsigned*)&xb[(size_t)t * ND];
    float w = wsh[sl * 32 + t];
    ax += w * bf2f((ushort_t)(u & 0xffffu));
    ay += w * bf2f((ushort_t)(u >> 16));
  }
  red[sl][dd][0] = ax;
  red[sl][dd][1] = ay;
  __syncthreads();
  if (sl == 0) {
    float2 o;
    o.x = red[0][dd][0] + red[1][dd][0] + red[2][dd][0] + red[3][dd][0];
    o.y = red[0][dd][1] + red[1][dd][1] + red[2][dd][1] + red[3][dd][1];
    *(float2*)&xbar[(size_t)b * ND + d] = o;
  }
}

// ------ K6: fused elig epilogues. path0: V (hbar,Wv,bv,csum,eV0->outV) -----
//                                  path1: K (xbar,Wk,bk,wsum,eK0->outK)
// grid (16 dchunks, 16 bpairs, 2 paths), 256 thr = 64 d x 4 e-slices
__global__ __launch_bounds__(256) void eligvk_kernel(const float* __restrict__ hbar,
                                                     const float* __restrict__ xbar,
                                                     const float* __restrict__ Wv,
                                                     const float* __restrict__ Wk,
                                                     const float* __restrict__ bv,
                                                     const float* __restrict__ bk,
                                                     const float* __restrict__ eV0,
                                                     const float* __restrict__ eK0,
                                                     const float* __restrict__ Abuf,
                                                     const float* __restrict__ csum,
                                                     const float* __restrict__ wsum,
                                                     float* __restrict__ outV,
                                                     float* __restrict__ outK) {
  int path = blockIdx.z;
  const float* src  = path ? xbar : hbar;
  const float* W    = path ? Wk : Wv;
  const float* bias = path ? bk : bv;
  const float* coef = path ? wsum : csum;
  const float* e0   = path ? eK0 : eV0;
  float* out        = path ? outK : outV;
  int dd = threadIdx.x & 63, esl = threadIdx.x >> 6;
  int d = blockIdx.x * 64 + dd;
  int b0 = blockIdx.y * 2;
  __shared__ float hs[2][ND];
  __shared__ float red[4][2][64];
  for (int i = threadIdx.x; i < 2 * ND; i += 256) {
    int bb = i >> 10, e = i & 1023;
    hs[bb][e] = src[(size_t)(b0 + bb) * ND + e];
  }
  __syncthreads();
  float a0 = 0.f, a1 = 0.f;
  const float* wcol = W + d;
#pragma unroll 8
  for (int ei = 0; ei < 256; ++ei) {
    int e = esl * 256 + ei;
    float w = wcol[(size_t)e * ND];
    a0 += hs[0][e] * w;
    a1 += hs[1][e] * w;
  }
  red[esl][0][dd] = a0;
  red[esl][1][dd] = a1;
  __syncthreads();
  if (threadIdx.x < 128) {
    int bb = threadIdx.x >> 6, ddd = threadIdx.x & 63;
    int b = b0 + bb;
    int dg = blockIdx.x * 64 + ddd;
    float s = red[0][bb][ddd] + red[1][bb][ddd] + red[2][bb][ddd] + red[3][bb][ddd];
    s += coef[b] * bias[dg];
    float A = Abuf[b];
#pragma unroll
    for (int r = 0; r < NR; ++r) {
      size_t idx = ((size_t)(b * NR + r)) * ND + dg;
      out[idx] = A * e0[idx] + s;
    }
  }
}

// ---------------- K7: y_pm (+ fused x->bf16 conversion) ----------------
__global__ __launch_bounds__(256) void ypm_kernel(const float* __restrict__ x,
                                                  const float* __restrict__ pmK,
                                                  const float* __restrict__ pmV,
                                                  const float* __restrict__ pma,
                                                  float* __restrict__ y,
                                                  ushort_t* __restrict__ Xb) {
  int p = blockIdx.x, b = blockIdx.y;
  int tid = threadIdx.x;
  const float* xr = x + ((size_t)b * NP + p) * ND;
  float xv[4];
  float ssq = 0.f;
#pragma unroll
  for (int i = 0; i < 4; ++i) {
    float v = xr[tid + 256 * i];
    xv[i] = v;
    ssq += v * v;
  }
  // fused convx
  ushort_t* xbr = Xb + ((size_t)b * NP + p) * ND;
#pragma unroll
  for (int i = 0; i < 4; ++i) xbr[tid + 256 * i] = f2bf(xv[i]);
  float sc[NR];
#pragma unroll
  for (int r = 0; r < NR; ++r) {
    const float* kr = pmK + ((size_t)b * NR + r) * ND;
    float s = 0.f;
#pragma unroll
    for (int i = 0; i < 4; ++i) s += xv[i] * kr[tid + 256 * i];
    sc[r] = s;
  }
#pragma unroll
  for (int off = 32; off > 0; off >>= 1) {
    ssq += __shfl_xor(ssq, off);
#pragma unroll
    for (int r = 0; r < NR; ++r) sc[r] += __shfl_xor(sc[r], off);
  }
  __shared__ float red[4][NR + 1];
  int wave = tid >> 6, lane = tid & 63;
  if (lane == 0) {
    red[wave][0] = ssq;
    for (int r = 0; r < NR; ++r) red[wave][r + 1] = sc[r];
  }
  __syncthreads();
  float tot = red[0][0] + red[1][0] + red[2][0] + red[3][0];
  float inv = 1.f / fmaxf(sqrtf(tot), EPSN);
  float w[NR];
#pragma unroll
  for (int r = 0; r < NR; ++r)
    w[r] = pma[b * NR + r] *
           (red[0][r + 1] + red[1][r + 1] + red[2][r + 1] + red[3][r + 1]) * inv;
  float* yr = y + ((size_t)b * NP + p) * ND;
#pragma unroll
  for (int i = 0; i < 4; ++i) {
    int d = tid + 256 * i;
    float acc = 0.f;
#pragma unroll
    for (int r = 0; r < NR; ++r) acc += w[r] * pmV[((size_t)b * NR + r) * ND + d];
    yr[d] = acc;
  }
}

extern "C" void kernel_launch(void* const* d_in, const int* in_sizes, int n_in,
                              void* d_out, int out_size, void* d_ws, size_t ws_size,
                              hipStream_t stream) {
  (void)in_sizes; (void)n_in; (void)out_size; (void)ws_size;
  const float* x_all    = (const float*)d_in[0];
  const float* h_all    = (const float*)d_in[1];
  const float* surprise = (const float*)d_in[2];
  const void*  mask     = d_in[3];
  const float* pmK      = (const float*)d_in[4];
  const float* pmV      = (const float*)d_in[5];
  const float* pma      = (const float*)d_in[6];
  const float* eK0      = (const float*)d_in[7];
  const float* eV0      = (const float*)d_in[8];
  const float* Wk       = (const float*)d_in[9];
  const float* bk       = (const float*)d_in[10];
  const float* Wv       = (const float*)d_in[11];
  const float* bv       = (const float*)d_in[12];

  float* y    = (float*)d_out;
  float* outK = y + (size_t)NB * NP * ND;
  float* outV = outK + (size_t)NB * NR * ND;

  char* w = (char*)d_ws;
  float* c       = (float*)w; w += NB * NP * 4;                // 16 KB
  float* Abuf    = (float*)w; w += 256;
  float* csum    = (float*)w; w += 256;
  float* wsum    = (float*)w; w += 256;
  float* hbar    = (float*)w; w += NB * ND * 4;                // 128 KB
  float* xbar    = (float*)w; w += NB * ND * 4;                // 128 KB
  float* norms2p = (float*)w; w += (size_t)8 * NB * NP * 4;    // 128 KB
  ushort_t* WkT  = (ushort_t*)w; w += (size_t)ND * ND * 2;     // 2 MB
  ushort_t* Xb   = (ushort_t*)w; w += (size_t)NB * NP * ND * 2;  // 8 MB

  scalars_kernel<<<NB, NP, 0, stream>>>(surprise, mask, c, Abuf, csum);
  hbar_kernel<<<dim3(ND / 64, NB), 256, 0, stream>>>(h_all, c, hbar);
  ypm_kernel<<<dim3(NP, NB), 256, 0, stream>>>(x_all, pmK, pmV, pma, y, Xb);
  convwt_kernel<<<dim3(ND / 64, ND / 64), 256, 0, stream>>>(Wk, WkT);
  kgemm_norms<<<dim3(NB, ND / 128), 512, 0, stream>>>(Xb, WkT, bk, norms2p);
  xbarw_kernel<<<dim3(ND / 128, NB), 256, 0, stream>>>(Xb, norms2p, c, xbar, wsum);
  eligvk_kernel<<<dim3(ND / 64, NB / 2, 2), 256, 0, stream>>>(
      hbar, xbar, Wv, Wk, bv, bk, eV0, eK0, Abuf, csum, wsum, outV, outK);
}

// Round 6
// 80.572 us; speedup vs baseline: 2.9917x; 1.1599x over previous
//
#include <hip/hip_runtime.h>
#include <cstdint>
#include <cstddef>

#define NB 32
#define NP 128
#define NR 16
#define ND 1024
#define RHOC 0.97f
#define EPSN 1e-8f

typedef short bf16x8 __attribute__((ext_vector_type(8)));
typedef float f32x4 __attribute__((ext_vector_type(4)));
typedef unsigned short ushort_t;

__device__ inline ushort_t f2bf(float f) {
  unsigned u = __float_as_uint(f);
  unsigned r = (u + 0x7fffu + ((u >> 16) & 1u)) >> 16;
  return (ushort_t)r;
}
__device__ inline float bf2f(ushort_t v) {
  return __uint_as_float(((unsigned)v) << 16);
}
__device__ inline void gload16(const void* g, void* l) {
  __builtin_amdgcn_global_load_lds(
      (const __attribute__((address_space(1))) void*)g,
      (__attribute__((address_space(3))) void*)l, 16, 0, 0);
}

// ---------------- K1: per-(b,t) scalars: c, A, csum (+mask dtype detect) ----
__global__ void scalars_kernel(const float* __restrict__ surprise,
                               const void* __restrict__ mask,
                               float* __restrict__ c,
                               float* __restrict__ Abuf,
                               float* __restrict__ csum) {
  int b = blockIdx.x;
  int t = threadIdx.x;  // 128 threads
  __shared__ float a_sh[NP];
  __shared__ float suf[NP + 1];
  __shared__ float red[NP];
  __shared__ int isu8;
  if (t == 0) isu8 = 0;
  __syncthreads();
  // detect: int32 storage has all bytes at idx%4!=0 equal to zero
  const unsigned char* mb = (const unsigned char*)mask;
  int v = 0;
  for (int i = t; i < NB * NP; i += NP) {
    if ((i & 3) != 0 && mb[i] != 0) v = 1;
  }
  if (v) isu8 = 1;
  __syncthreads();
  float g = surprise[b * NP + t] * 0.2f;
  g = fminf(fmaxf(g, 0.f), 1.f);
  int mv;
  if (isu8) mv = mb[b * NP + t];
  else      mv = ((const int*)mask)[b * NP + t];
  float a = RHOC * (mv ? 0.f : 1.f);
  a_sh[t] = a;
  __syncthreads();
  if (t == 0) {
    float p = 1.f;
    suf[NP] = 1.f;
    for (int s = NP - 1; s >= 0; --s) { p *= a_sh[s]; suf[s] = p; }
  }
  __syncthreads();
  float cv = g * suf[t + 1];
  c[b * NP + t] = cv;
  red[t] = cv;
  __syncthreads();
  for (int off = 64; off > 0; off >>= 1) {
    if (t < off) red[t] += red[t + off];
    __syncthreads();
  }
  if (t == 0) { csum[b] = red[0]; Abuf[b] = suf[0]; }
}

// ------- K2: convx: x -> bf16 Xb + f32 row norms (one row per block) -------
__global__ __launch_bounds__(256) void convx_kernel(const float* __restrict__ x,
                                                    ushort_t* __restrict__ Xb,
                                                    float* __restrict__ xnorm) {
  int row = blockIdx.x;
  int t = threadIdx.x;
  float4 v = *(const float4*)&x[(size_t)row * ND + t * 4];
  ushort4 o;
  o.x = f2bf(v.x); o.y = f2bf(v.y); o.z = f2bf(v.z); o.w = f2bf(v.w);
  *(ushort4*)&Xb[(size_t)row * ND + t * 4] = o;
  float ss = v.x * v.x + v.y * v.y + v.z * v.z + v.w * v.w;
#pragma unroll
  for (int off = 32; off > 0; off >>= 1) ss += __shfl_xor(ss, off);
  __shared__ float red[4];
  int wave = t >> 6, lane = t & 63;
  if (lane == 0) red[wave] = ss;
  __syncthreads();
  if (t == 0) xnorm[row] = sqrtf(red[0] + red[1] + red[2] + red[3]);
}

// ------- K3: hbar[b][d] = sum_t c[b,t]*h[b,t,d]  (full-t in one block) -----
__global__ __launch_bounds__(256) void hbar_kernel(const float* __restrict__ h,
                                                   const float* __restrict__ c,
                                                   float* __restrict__ hbar) {
  int b = blockIdx.y;
  int dd = threadIdx.x & 63, sl = threadIdx.x >> 6;
  int d = blockIdx.x * 64 + dd;
  __shared__ float cs[NP];
  __shared__ float red[4][64];
  if (threadIdx.x < NP) cs[threadIdx.x] = c[b * NP + threadIdx.x];
  __syncthreads();
  const float* hb = h + ((size_t)b * NP + sl * 32) * ND + d;
  float acc = 0.f;
#pragma unroll
  for (int t = 0; t < 32; ++t) acc += cs[sl * 32 + t] * hb[(size_t)t * ND];
  red[sl][dd] = acc;
  __syncthreads();
  if (sl == 0)
    hbar[(size_t)b * ND + d] = red[0][dd] + red[1][dd] + red[2][dd] + red[3][dd];
}

// ---------------- K4: convert Wk -> bf16 transposed [N][K] ----------------
__global__ __launch_bounds__(256) void convwt_kernel(const float* __restrict__ W,
                                                     ushort_t* __restrict__ WT) {
  __shared__ ushort_t t[64][65];
  int tid = threadIdx.x;
  int k0 = blockIdx.y * 64, n0 = blockIdx.x * 64;
#pragma unroll
  for (int i = 0; i < 16; ++i) {
    int r = i * 4 + (tid >> 6), cc = tid & 63;
    t[r][cc] = f2bf(W[(size_t)(k0 + r) * ND + n0 + cc]);
  }
  __syncthreads();
#pragma unroll
  for (int i = 0; i < 16; ++i) {
    int r = i * 4 + (tid >> 6), cc = tid & 63;
    WT[(size_t)(n0 + r) * ND + k0 + cc] = t[cc][r];
  }
}

// -------- K5: row norms^2 of (x @ W_k + b_k) via bf16 MFMA (no kraw store) -
__global__ __launch_bounds__(512) void kgemm_norms(const ushort_t* __restrict__ Xb,
                                                   const ushort_t* __restrict__ WT,
                                                   const float* __restrict__ bk,
                                                   float* __restrict__ norms2p) {
  __shared__ ushort_t As[128 * 64];  // [row][slot(16B)] swizzled
  __shared__ ushort_t Bs[128 * 64];
  __shared__ float sred[4][128];
  int tid = threadIdx.x;
  int lane = tid & 63, wid = tid >> 6;
  int wr = wid >> 2, wc = wid & 3;       // 2 x 4 wave grid
  int bm = blockIdx.x, bn = blockIdx.y;  // x fastest: bm%8 fixes XCD (A reuse)
  int m0 = bm * 128;
  int n0 = bn * 128;
  int lo = lane & 15, hi = lane >> 4;

  f32x4 acc[4][2] = {};

  for (int k0 = 0; k0 < ND; k0 += 64) {
#pragma unroll
    for (int i = 0; i < 2; ++i) {
      int sl = i * 512 + tid;
      int r = sl >> 3, s = sl & 7;
      int gk = k0 + ((s ^ (r & 7)) << 3);
      gload16(&Xb[(size_t)(m0 + r) * ND + gk], &As[sl << 3]);
    }
#pragma unroll
    for (int i = 0; i < 2; ++i) {
      int sl = i * 512 + tid;
      int r = sl >> 3, s = sl & 7;
      int gk = k0 + ((s ^ (r & 7)) << 3);
      gload16(&WT[(size_t)(n0 + r) * ND + gk], &Bs[sl << 3]);
    }
    __syncthreads();
#pragma unroll
    for (int ksl = 0; ksl < 2; ++ksl) {
      bf16x8 af[4], bfr[2];
#pragma unroll
      for (int mi = 0; mi < 4; ++mi) {
        int r = wr * 64 + mi * 16 + lo;
        int cchunk = ksl * 4 + hi;
        int s = cchunk ^ (r & 7);
        af[mi] = *(const bf16x8*)&As[(r << 6) + (s << 3)];
      }
#pragma unroll
      for (int ni = 0; ni < 2; ++ni) {
        int r = wc * 32 + ni * 16 + lo;
        int cchunk = ksl * 4 + hi;
        int s = cchunk ^ (r & 7);
        bfr[ni] = *(const bf16x8*)&Bs[(r << 6) + (s << 3)];
      }
#pragma unroll
      for (int mi = 0; mi < 4; ++mi)
#pragma unroll
        for (int ni = 0; ni < 2; ++ni)
          acc[mi][ni] = __builtin_amdgcn_mfma_f32_16x16x32_bf16(
              af[mi], bfr[ni], acc[mi][ni], 0, 0, 0);
    }
    __syncthreads();
  }

  // epilogue: bias + per-row partial ssq over this wave's 32-col span
  float bkv[2];
#pragma unroll
  for (int ni = 0; ni < 2; ++ni) bkv[ni] = bk[n0 + wc * 32 + ni * 16 + lo];
#pragma unroll
  for (int mi = 0; mi < 4; ++mi) {
#pragma unroll
    for (int j = 0; j < 4; ++j) {
      float ss = 0.f;
#pragma unroll
      for (int ni = 0; ni < 2; ++ni) {
        float v = acc[mi][ni][j] + bkv[ni];
        ss += v * v;
      }
      ss += __shfl_xor(ss, 1);
      ss += __shfl_xor(ss, 2);
      ss += __shfl_xor(ss, 4);
      ss += __shfl_xor(ss, 8);
      if (lo == 0) sred[wc][wr * 64 + mi * 16 + hi * 4 + j] = ss;
    }
  }
  __syncthreads();
  if (tid < 128)
    norms2p[(size_t)bn * (NB * NP) + m0 + tid] =
        sred[0][tid] + sred[1][tid] + sred[2][tid] + sred[3][tid];
}

// ------ K6: wsh = c/max(norm,eps); xbar[b,d] = sum_t wsh*x_bf16; wsum ------
__global__ __launch_bounds__(256) void xbarw_kernel(const ushort_t* __restrict__ Xb,
                                                    const float* __restrict__ norms2p,
                                                    const float* __restrict__ c,
                                                    float* __restrict__ xbar,
                                                    float* __restrict__ wsum) {
  int b = blockIdx.y;
  int dd = threadIdx.x & 63, sl = threadIdx.x >> 6;
  int d = blockIdx.x * 128 + dd * 2;
  __shared__ float wsh[NP];
  __shared__ float red[4][64][2];
  if (threadIdx.x < NP) {
    float s = 0.f;
#pragma unroll
    for (int bn = 0; bn < 8; ++bn)
      s += norms2p[(size_t)bn * (NB * NP) + b * NP + threadIdx.x];
    wsh[threadIdx.x] = c[b * NP + threadIdx.x] / fmaxf(sqrtf(s), EPSN);
  }
  __syncthreads();
  if (blockIdx.x == 0 && threadIdx.x == 0) {
    float s = 0.f;
    for (int t = 0; t < NP; ++t) s += wsh[t];
    wsum[b] = s;
  }
  const ushort_t* xb = Xb + ((size_t)b * NP + sl * 32) * ND + d;
  float ax = 0.f, ay = 0.f;
#pragma unroll
  for (int t = 0; t < 32; ++t) {
    unsigned u = *(const unsigned*)&xb[(size_t)t * ND];
    float w = wsh[sl * 32 + t];
    ax += w * bf2f((ushort_t)(u & 0xffffu));
    ay += w * bf2f((ushort_t)(u >> 16));
  }
  red[sl][dd][0] = ax;
  red[sl][dd][1] = ay;
  __syncthreads();
  if (sl == 0) {
    float2 o;
    o.x = red[0][dd][0] + red[1][dd][0] + red[2][dd][0] + red[3][dd][0];
    o.y = red[0][dd][1] + red[1][dd][1] + red[2][dd][1] + red[3][dd][1];
    *(float2*)&xbar[(size_t)b * ND + d] = o;
  }
}

// ------ K7: fused elig epilogues. path0: V; path1: K -----------------------
__global__ __launch_bounds__(256) void eligvk_kernel(const float* __restrict__ hbar,
                                                     const float* __restrict__ xbar,
                                                     const float* __restrict__ Wv,
                                                     const float* __restrict__ Wk,
                                                     const float* __restrict__ bv,
                                                     const float* __restrict__ bk,
                                                     const float* __restrict__ eV0,
                                                     const float* __restrict__ eK0,
                                                     const float* __restrict__ Abuf,
                                                     const float* __restrict__ csum,
                                                     const float* __restrict__ wsum,
                                                     float* __restrict__ outV,
                                                     float* __restrict__ outK) {
  int path = blockIdx.z;
  const float* src  = path ? xbar : hbar;
  const float* W    = path ? Wk : Wv;
  const float* bias = path ? bk : bv;
  const float* coef = path ? wsum : csum;
  const float* e0   = path ? eK0 : eV0;
  float* out        = path ? outK : outV;
  int dd = threadIdx.x & 63, esl = threadIdx.x >> 6;
  int d = blockIdx.x * 64 + dd;
  int b0 = blockIdx.y * 2;
  __shared__ float hs[2][ND];
  __shared__ float red[4][2][64];
  for (int i = threadIdx.x; i < 2 * ND; i += 256) {
    int bb = i >> 10, e = i & 1023;
    hs[bb][e] = src[(size_t)(b0 + bb) * ND + e];
  }
  __syncthreads();
  float a0 = 0.f, a1 = 0.f;
  const float* wcol = W + d;
#pragma unroll 8
  for (int ei = 0; ei < 256; ++ei) {
    int e = esl * 256 + ei;
    float w = wcol[(size_t)e * ND];
    a0 += hs[0][e] * w;
    a1 += hs[1][e] * w;
  }
  red[esl][0][dd] = a0;
  red[esl][1][dd] = a1;
  __syncthreads();
  if (threadIdx.x < 128) {
    int bb = threadIdx.x >> 6, ddd = threadIdx.x & 63;
    int b = b0 + bb;
    int dg = blockIdx.x * 64 + ddd;
    float s = red[0][bb][ddd] + red[1][bb][ddd] + red[2][bb][ddd] + red[3][bb][ddd];
    s += coef[b] * bias[dg];
    float A = Abuf[b];
#pragma unroll
    for (int r = 0; r < NR; ++r) {
      size_t idx = ((size_t)(b * NR + r)) * ND + dg;
      out[idx] = A * e0[idx] + s;
    }
  }
}

// -------- K8: y_pm via MFMA QK^T + VALU PV. block = (b, 16-p chunk) --------
// 4 waves; QK: K=1024 split across waves (8 MFMA each); PV: K=16 in VALU.
__global__ __launch_bounds__(256) void ypm2_kernel(const ushort_t* __restrict__ Xb,
                                                   const float* __restrict__ pmK,
                                                   const float* __restrict__ pmV,
                                                   const float* __restrict__ pma,
                                                   const float* __restrict__ xnorm,
                                                   float* __restrict__ y) {
  int b = blockIdx.y, p0 = blockIdx.x * 16;
  int tid = threadIdx.x;
  int lane = tid & 63, wid = tid >> 6;
  int lo = lane & 15, hi = lane >> 4;
  __shared__ ushort_t xs[16 * 1024];  // [row][slot of 8 bf16], slot^=(row&7)
  __shared__ ushort_t ks[16 * 1024];
  __shared__ float sred[4][16][17];
  __shared__ float wls[16][16];

  // stage x rows (global-source swizzle, linear LDS dest via gload16)
#pragma unroll
  for (int i = 0; i < 8; ++i) {
    int sl = i * 256 + tid;
    int r = sl >> 7, s = sl & 127;
    int gd = (s ^ (r & 7)) << 3;
    gload16(&Xb[((size_t)(b * NP + p0 + r)) * ND + gd], &xs[(size_t)sl << 3]);
  }
  // stage pmK rows (reg-staged f32->bf16, swizzled LDS dest)
#pragma unroll
  for (int i = 0; i < 8; ++i) {
    int sl = i * 256 + tid;
    int r = sl >> 7, s = sl & 127;
    const float4* src = (const float4*)&pmK[((size_t)(b * NR + r)) * ND + (s << 3)];
    float4 v0 = src[0], v1 = src[1];
    union { bf16x8 v; ushort_t u[8]; } pk;
    pk.u[0] = f2bf(v0.x); pk.u[1] = f2bf(v0.y);
    pk.u[2] = f2bf(v0.z); pk.u[3] = f2bf(v0.w);
    pk.u[4] = f2bf(v1.x); pk.u[5] = f2bf(v1.y);
    pk.u[6] = f2bf(v1.z); pk.u[7] = f2bf(v1.w);
    int ds = (r << 7) | (s ^ (r & 7));
    *(bf16x8*)&ks[(size_t)ds << 3] = pk.v;
  }
  __syncthreads();

  // QK^T: wave wid covers K range [wid*256, wid*256+256)
  f32x4 sc = {};
#pragma unroll
  for (int ki = 0; ki < 8; ++ki) {
    int kstep = wid * 8 + ki;
    int sa = kstep * 4 + hi;
    bf16x8 af = *(const bf16x8*)&xs[(size_t)((lo << 7) | (sa ^ (lo & 7))) << 3];
    bf16x8 bf = *(const bf16x8*)&ks[(size_t)((lo << 7) | (sa ^ (lo & 7))) << 3];
    sc = __builtin_amdgcn_mfma_f32_16x16x32_bf16(af, bf, sc, 0, 0, 0);
  }
#pragma unroll
  for (int j = 0; j < 4; ++j) sred[wid][hi * 4 + j][lo] = sc[j];
  __syncthreads();
  {
    int p = tid >> 4, r = tid & 15;
    float s = sred[0][p][r] + sred[1][p][r] + sred[2][p][r] + sred[3][p][r];
    float xn = xnorm[b * NP + p0 + p];
    wls[p][r] = pma[b * NR + r] * s / fmaxf(xn, EPSN);
  }
  __syncthreads();

  // PV: thread owns 4 d's; pmV f32 in regs, w broadcast from LDS
  float4 v[16];
#pragma unroll
  for (int r = 0; r < 16; ++r)
    v[r] = *(const float4*)&pmV[((size_t)(b * NR + r)) * ND + tid * 4];
#pragma unroll
  for (int p = 0; p < 16; ++p) {
    float4 a = {0.f, 0.f, 0.f, 0.f};
#pragma unroll
    for (int r = 0; r < 16; ++r) {
      float w = wls[p][r];
      a.x += w * v[r].x; a.y += w * v[r].y;
      a.z += w * v[r].z; a.w += w * v[r].w;
    }
    *(float4*)&y[((size_t)(b * NP + p0 + p)) * ND + tid * 4] = a;
  }
}

extern "C" void kernel_launch(void* const* d_in, const int* in_sizes, int n_in,
                              void* d_out, int out_size, void* d_ws, size_t ws_size,
                              hipStream_t stream) {
  (void)in_sizes; (void)n_in; (void)out_size; (void)ws_size;
  const float* x_all    = (const float*)d_in[0];
  const float* h_all    = (const float*)d_in[1];
  const float* surprise = (const float*)d_in[2];
  const void*  mask     = d_in[3];
  const float* pmK      = (const float*)d_in[4];
  const float* pmV      = (const float*)d_in[5];
  const float* pma      = (const float*)d_in[6];
  const float* eK0      = (const float*)d_in[7];
  const float* eV0      = (const float*)d_in[8];
  const float* Wk       = (const float*)d_in[9];
  const float* bk       = (const float*)d_in[10];
  const float* Wv       = (const float*)d_in[11];
  const float* bv       = (const float*)d_in[12];

  float* y    = (float*)d_out;
  float* outK = y + (size_t)NB * NP * ND;
  float* outV = outK + (size_t)NB * NR * ND;

  char* w = (char*)d_ws;
  float* c       = (float*)w; w += NB * NP * 4;                // 16 KB
  float* Abuf    = (float*)w; w += 256;
  float* csum    = (float*)w; w += 256;
  float* wsum    = (float*)w; w += 256;
  float* hbar    = (float*)w; w += NB * ND * 4;                // 128 KB
  float* xbar    = (float*)w; w += NB * ND * 4;                // 128 KB
  float* norms2p = (float*)w; w += (size_t)8 * NB * NP * 4;    // 128 KB
  float* xnorm   = (float*)w; w += NB * NP * 4;                // 16 KB
  ushort_t* WkT  = (ushort_t*)w; w += (size_t)ND * ND * 2;     // 2 MB
  ushort_t* Xb   = (ushort_t*)w; w += (size_t)NB * NP * ND * 2;  // 8 MB

  scalars_kernel<<<NB, NP, 0, stream>>>(surprise, mask, c, Abuf, csum);
  convx_kernel<<<NB * NP, 256, 0, stream>>>(x_all, Xb, xnorm);
  convwt_kernel<<<dim3(ND / 64, ND / 64), 256, 0, stream>>>(Wk, WkT);
  hbar_kernel<<<dim3(ND / 64, NB), 256, 0, stream>>>(h_all, c, hbar);
  kgemm_norms<<<dim3(NB, ND / 128), 512, 0, stream>>>(Xb, WkT, bk, norms2p);
  xbarw_kernel<<<dim3(ND / 128, NB), 256, 0, stream>>>(Xb, norms2p, c, xbar, wsum);
  ypm2_kernel<<<dim3(NP / 16, NB), 256, 0, stream>>>(Xb, pmK, pmV, pma, xnorm, y);
  eligvk_kernel<<<dim3(ND / 64, NB / 2, 2), 256, 0, stream>>>(
      hbar, xbar, Wv, Wk, bv, bk, eV0, eK0, Abuf, csum, wsum, outV, outK);
}

// Round 7
// 57.065 us; speedup vs baseline: 4.2242x; 1.4119x over previous
//
#include <hip/hip_runtime.h>
#include <cstdint>
#include <cstddef>

#define NB 32
#define NP 128
#define NR 16
#define ND 1024
#define RHOC 0.97f
#define EPSN 1e-8f

typedef short bf16x8 __attribute__((ext_vector_type(8)));
typedef float f32x4 __attribute__((ext_vector_type(4)));
typedef unsigned short u16x8 __attribute__((ext_vector_type(8)));
typedef unsigned short ushort_t;

__device__ inline ushort_t f2bf(float f) {
  unsigned u = __float_as_uint(f);
  unsigned r = (u + 0x7fffu + ((u >> 16) & 1u)) >> 16;
  return (ushort_t)r;
}
__device__ inline float bf2f(ushort_t v) {
  return __uint_as_float(((unsigned)v) << 16);
}
__device__ inline void gload16(const void* g, void* l) {
  __builtin_amdgcn_global_load_lds(
      (const __attribute__((address_space(1))) void*)g,
      (__attribute__((address_space(3))) void*)l, 16, 0, 0);
}

// ============ D1: prep = scalars(32) + convx(4096) + convwt(256) + convpk(256)
__global__ __launch_bounds__(256) void prep_kernel(
    const float* __restrict__ surprise, const void* __restrict__ mask,
    const float* __restrict__ x, const float* __restrict__ Wk,
    const float* __restrict__ pmK,
    float* __restrict__ c, float* __restrict__ Abuf, float* __restrict__ csum,
    ushort_t* __restrict__ Xb, float* __restrict__ xnorm,
    ushort_t* __restrict__ WkT, ushort_t* __restrict__ pmKb) {
  __shared__ __align__(16) char smem[8448];
  int bid = blockIdx.x;
  int t = threadIdx.x;
  if (bid < NB) {
    // ---- scalars: c, A, csum (+mask dtype detect) ----
    float* a_sh = (float*)smem;        // 128
    float* suf  = a_sh + 128;          // 129
    float* redc = suf + 129;           // 128
    int*   isu8 = (int*)(redc + 128);
    int b = bid;
    if (t == 0) *isu8 = 0;
    __syncthreads();
    const unsigned char* mb = (const unsigned char*)mask;
    int v = 0;
    for (int i = t; i < NB * NP; i += 256)
      if ((i & 3) != 0 && mb[i] != 0) v = 1;
    if (v) *isu8 = 1;   // benign race: all writers write 1
    __syncthreads();
    int u8 = *isu8;
    if (t < NP) {
      int mv = u8 ? mb[b * NP + t] : ((const int*)mask)[b * NP + t];
      a_sh[t] = RHOC * (mv ? 0.f : 1.f);
    }
    __syncthreads();
    if (t == 0) {
      float p = 1.f;
      suf[NP] = 1.f;
      for (int s = NP - 1; s >= 0; --s) { p *= a_sh[s]; suf[s] = p; }
    }
    __syncthreads();
    if (t < NP) {
      float g = fminf(fmaxf(surprise[b * NP + t] * 0.2f, 0.f), 1.f);
      float cv = g * suf[t + 1];
      c[b * NP + t] = cv;
      redc[t] = cv;
    }
    __syncthreads();
    for (int off = 64; off > 0; off >>= 1) {
      if (t < off) redc[t] += redc[t + off];
      __syncthreads();
    }
    if (t == 0) { csum[b] = redc[0]; Abuf[b] = suf[0]; }
  } else if (bid < NB + NB * NP) {
    // ---- convx: one x-row -> bf16 + norm ----
    int row = bid - NB;
    float* red = (float*)smem;
    float4 vv = *(const float4*)&x[(size_t)row * ND + t * 4];
    ushort4 o;
    o.x = f2bf(vv.x); o.y = f2bf(vv.y); o.z = f2bf(vv.z); o.w = f2bf(vv.w);
    *(ushort4*)&Xb[(size_t)row * ND + t * 4] = o;
    float ss = vv.x * vv.x + vv.y * vv.y + vv.z * vv.z + vv.w * vv.w;
#pragma unroll
    for (int off = 32; off > 0; off >>= 1) ss += __shfl_xor(ss, off);
    int wave = t >> 6, lane = t & 63;
    if (lane == 0) red[wave] = ss;
    __syncthreads();
    if (t == 0) xnorm[row] = sqrtf(red[0] + red[1] + red[2] + red[3]);
  } else if (bid < NB + NB * NP + 256) {
    // ---- convwt: Wk -> bf16 transposed [N][K] ----
    int id2 = bid - (NB + NB * NP);
    ushort_t (*tt)[65] = (ushort_t(*)[65])smem;
    int k0 = (id2 >> 4) * 64, n0 = (id2 & 15) * 64;
#pragma unroll
    for (int i = 0; i < 16; ++i) {
      int r = i * 4 + (t >> 6), cc = t & 63;
      tt[r][cc] = f2bf(Wk[(size_t)(k0 + r) * ND + n0 + cc]);
    }
    __syncthreads();
#pragma unroll
    for (int i = 0; i < 16; ++i) {
      int r = i * 4 + (t >> 6), cc = t & 63;
      WkT[(size_t)(n0 + r) * ND + k0 + cc] = tt[cc][r];
    }
  } else {
    // ---- convpk: pmK f32 -> bf16, 2048 elems/block ----
    int id3 = bid - (NB + NB * NP + 256);
    size_t base = (size_t)id3 * 2048 + t * 8;
    float4 a = *(const float4*)&pmK[base];
    float4 bq = *(const float4*)&pmK[base + 4];
    u16x8 o;
    o[0] = f2bf(a.x); o[1] = f2bf(a.y); o[2] = f2bf(a.z); o[3] = f2bf(a.w);
    o[4] = f2bf(bq.x); o[5] = f2bf(bq.y); o[6] = f2bf(bq.z); o[7] = f2bf(bq.w);
    *(u16x8*)&pmKb[base] = o;
  }
}

// ============ D2: main = kgemm_norms(512: BM=128 BN=64) + hbar(512) ==========
__global__ __launch_bounds__(256) void main_kernel(
    const ushort_t* __restrict__ Xb, const ushort_t* __restrict__ WkT,
    const float* __restrict__ bk, float* __restrict__ norms2p,
    const float* __restrict__ h, const float* __restrict__ c,
    float* __restrict__ hbar) {
  __shared__ __align__(16) char smem[25600];
  int bid = blockIdx.x;
  int tid = threadIdx.x;
  if (bid < 512) {
    // ---- kgemm_norms: tile 128x64, BK=64, 4 waves (2x2), wave 64x32 ----
    ushort_t* As = (ushort_t*)smem;         // 128*64
    ushort_t* Bs = As + 128 * 64;           // 64*64
    float* sred = (float*)(Bs + 64 * 64);   // [2][128]
    int lane = tid & 63, wid = tid >> 6;
    int wr = wid >> 1, wc = wid & 1;
    int bm = bid & 31, bn = bid >> 5;  // bm fastest: same-bm -> same XCD
    int m0 = bm * 128, n0 = bn * 64;
    int lo = lane & 15, hi = lane >> 4;
    f32x4 acc[4][2] = {};
    for (int k0 = 0; k0 < ND; k0 += 64) {
#pragma unroll
      for (int i = 0; i < 4; ++i) {
        int sl = i * 256 + tid;
        int r = sl >> 3, s = sl & 7;
        int gk = k0 + ((s ^ (r & 7)) << 3);
        gload16(&Xb[(size_t)(m0 + r) * ND + gk], &As[sl << 3]);
      }
#pragma unroll
      for (int i = 0; i < 2; ++i) {
        int sl = i * 256 + tid;
        int r = sl >> 3, s = sl & 7;
        int gk = k0 + ((s ^ (r & 7)) << 3);
        gload16(&WkT[(size_t)(n0 + r) * ND + gk], &Bs[sl << 3]);
      }
      __syncthreads();
#pragma unroll
      for (int ksl = 0; ksl < 2; ++ksl) {
        bf16x8 af[4], bfr[2];
#pragma unroll
        for (int mi = 0; mi < 4; ++mi) {
          int r = wr * 64 + mi * 16 + lo;
          int s = (ksl * 4 + hi) ^ (r & 7);
          af[mi] = *(const bf16x8*)&As[(r << 6) + (s << 3)];
        }
#pragma unroll
        for (int ni = 0; ni < 2; ++ni) {
          int r = wc * 32 + ni * 16 + lo;
          int s = (ksl * 4 + hi) ^ (r & 7);
          bfr[ni] = *(const bf16x8*)&Bs[(r << 6) + (s << 3)];
        }
#pragma unroll
        for (int mi = 0; mi < 4; ++mi)
#pragma unroll
          for (int ni = 0; ni < 2; ++ni)
            acc[mi][ni] = __builtin_amdgcn_mfma_f32_16x16x32_bf16(
                af[mi], bfr[ni], acc[mi][ni], 0, 0, 0);
      }
      __syncthreads();
    }
    float bkv[2];
#pragma unroll
    for (int ni = 0; ni < 2; ++ni) bkv[ni] = bk[n0 + wc * 32 + ni * 16 + lo];
#pragma unroll
    for (int mi = 0; mi < 4; ++mi) {
#pragma unroll
      for (int j = 0; j < 4; ++j) {
        float ss = 0.f;
#pragma unroll
        for (int ni = 0; ni < 2; ++ni) {
          float vv = acc[mi][ni][j] + bkv[ni];
          ss += vv * vv;
        }
        ss += __shfl_xor(ss, 1);
        ss += __shfl_xor(ss, 2);
        ss += __shfl_xor(ss, 4);
        ss += __shfl_xor(ss, 8);
        if (lo == 0) sred[wc * 128 + wr * 64 + mi * 16 + hi * 4 + j] = ss;
      }
    }
    __syncthreads();
    if (tid < 128)
      norms2p[(size_t)bn * (NB * NP) + m0 + tid] = sred[tid] + sred[128 + tid];
  } else {
    // ---- hbar ----
    int id2 = bid - 512;
    int b = id2 >> 4, dchunk = id2 & 15;
    float* cs = (float*)smem;     // 128
    float* red = cs + 128;        // [4][64]
    int dd = tid & 63, sl = tid >> 6;
    int d = dchunk * 64 + dd;
    if (tid < NP) cs[tid] = c[b * NP + tid];
    __syncthreads();
    const float* hb = h + ((size_t)b * NP + sl * 32) * ND + d;
    float acc = 0.f;
#pragma unroll
    for (int tt2 = 0; tt2 < 32; ++tt2) acc += cs[sl * 32 + tt2] * hb[(size_t)tt2 * ND];
    red[sl * 64 + dd] = acc;
    __syncthreads();
    if (sl == 0)
      hbar[(size_t)b * ND + d] = red[dd] + red[64 + dd] + red[128 + dd] + red[192 + dd];
  }
}

// ============ D3: mid = xbarw(256) + ypm2(256, LDS-light) ====================
__global__ __launch_bounds__(256) void mid_kernel(
    const ushort_t* __restrict__ Xb, const float* __restrict__ norms2p,
    const float* __restrict__ c, float* __restrict__ xbar,
    float* __restrict__ wsum, const ushort_t* __restrict__ pmKb,
    const float* __restrict__ pmV, const float* __restrict__ pma,
    const float* __restrict__ xnorm, float* __restrict__ y) {
  __shared__ __align__(16) char smem[5504];
  int bid = blockIdx.x;
  int tid = threadIdx.x;
  if (bid < 256) {
    // ---- xbarw: wsh = c/norm; xbar = sum_t wsh*x; wsum ----
    float* wsh = (float*)smem;      // 128
    float* red = wsh + NP;          // [4][64][2]
    int b = bid >> 3;
    int dd = tid & 63, sl = tid >> 6;
    int d = (bid & 7) * 128 + dd * 2;
    if (tid < NP) {
      float s = 0.f;
#pragma unroll
      for (int pc = 0; pc < 16; ++pc)
        s += norms2p[(size_t)pc * (NB * NP) + b * NP + tid];
      wsh[tid] = c[b * NP + tid] / fmaxf(sqrtf(s), EPSN);
    }
    __syncthreads();
    if ((bid & 7) == 0 && tid == 0) {
      float s = 0.f;
      for (int t2 = 0; t2 < NP; ++t2) s += wsh[t2];
      wsum[b] = s;
    }
    const ushort_t* xb = Xb + ((size_t)b * NP + sl * 32) * ND + d;
    float ax = 0.f, ay = 0.f;
#pragma unroll
    for (int t2 = 0; t2 < 32; ++t2) {
      unsigned u = *(const unsigned*)&xb[(size_t)t2 * ND];
      float w = wsh[sl * 32 + t2];
      ax += w * bf2f((ushort_t)(u & 0xffffu));
      ay += w * bf2f((ushort_t)(u >> 16));
    }
    red[(sl * 64 + dd) * 2 + 0] = ax;
    red[(sl * 64 + dd) * 2 + 1] = ay;
    __syncthreads();
    if (sl == 0) {
      float2 o;
      o.x = red[dd * 2] + red[(64 + dd) * 2] + red[(128 + dd) * 2] + red[(192 + dd) * 2];
      o.y = red[dd * 2 + 1] + red[(64 + dd) * 2 + 1] + red[(128 + dd) * 2 + 1] +
            red[(192 + dd) * 2 + 1];
      *(float2*)&xbar[(size_t)b * ND + d] = o;
    }
  } else {
    // ---- ypm2: QK^T MFMA direct-from-global; PV in VALU ----
    int id2 = bid - 256;
    int b = id2 >> 3, p0 = (id2 & 7) * 16;
    float* sredp = (float*)smem;        // [4][16][17]
    float* wls = sredp + 4 * 16 * 17;   // [16][16]
    int lane = tid & 63, wid = tid >> 6;
    int lo = lane & 15, hi = lane >> 4;
    // prefetch pmV
    float4 v[16];
#pragma unroll
    for (int r = 0; r < 16; ++r)
      v[r] = *(const float4*)&pmV[((size_t)(b * NR + r)) * ND + tid * 4];
    // QK^T: wave wid covers K range [wid*256, wid*256+256)
    const ushort_t* xrow = &Xb[((size_t)(b * NP + p0 + lo)) * ND];
    const ushort_t* krow = &pmKb[((size_t)(b * NR + lo)) * ND];
    f32x4 sc = {};
#pragma unroll
    for (int ki = 0; ki < 8; ++ki) {
      int koff = (wid * 8 + ki) * 32 + hi * 8;
      bf16x8 af = *(const bf16x8*)&xrow[koff];
      bf16x8 bf = *(const bf16x8*)&krow[koff];
      sc = __builtin_amdgcn_mfma_f32_16x16x32_bf16(af, bf, sc, 0, 0, 0);
    }
#pragma unroll
    for (int j = 0; j < 4; ++j) sredp[(wid * 16 + hi * 4 + j) * 17 + lo] = sc[j];
    __syncthreads();
    {
      int p = tid >> 4, r = tid & 15;
      float s = sredp[(p)*17 + r] + sredp[(16 + p) * 17 + r] +
                sredp[(32 + p) * 17 + r] + sredp[(48 + p) * 17 + r];
      wls[p * 16 + r] = pma[b * NR + r] * s / fmaxf(xnorm[b * NP + p0 + p], EPSN);
    }
    __syncthreads();
#pragma unroll
    for (int p = 0; p < 16; ++p) {
      float4 a = {0.f, 0.f, 0.f, 0.f};
#pragma unroll
      for (int r = 0; r < 16; ++r) {
        float w = wls[p * 16 + r];
        a.x += w * v[r].x; a.y += w * v[r].y;
        a.z += w * v[r].z; a.w += w * v[r].w;
      }
      *(float4*)&y[((size_t)(b * NP + p0 + p)) * ND + tid * 4] = a;
    }
  }
}

// ============ D4: vkbar: partial[path][esl][b][d] over 128-e slice ===========
// W read exactly once. 256 blocks: path(2) x esl(8) x dchunk(16); 256 thr.
__global__ __launch_bounds__(256) void vkbar_kernel(
    const float* __restrict__ hbar, const float* __restrict__ xbar,
    const float* __restrict__ Wv, const float* __restrict__ Wk,
    float* __restrict__ partials) {
  __shared__ __align__(16) float hst[128][36];  // transposed src slice, 18 KB
  int bid = blockIdx.x;
  int path = bid >> 7;
  int id2 = bid & 127;
  int esl = id2 >> 4, dchunk = id2 & 15;
  int e0 = esl * 128, d0 = dchunk * 64;
  const float* src = path ? xbar : hbar;
  const float* W = path ? Wk : Wv;
  int t = threadIdx.x;
#pragma unroll
  for (int i = 0; i < 16; ++i) {
    int idx = i * 256 + t;
    int bb = idx >> 7, e = idx & 127;
    hst[e][bb] = src[(size_t)bb * ND + e0 + e];
  }
  __syncthreads();
  int bg = t >> 6, dd = t & 63, d = d0 + dd;
  float acc[8] = {};
  for (int e = 0; e < 128; ++e) {
    float w = W[(size_t)(e0 + e) * ND + d];
    float4 h0 = *(const float4*)&hst[e][bg * 8];
    float4 h1 = *(const float4*)&hst[e][bg * 8 + 4];
    acc[0] += h0.x * w; acc[1] += h0.y * w; acc[2] += h0.z * w; acc[3] += h0.w * w;
    acc[4] += h1.x * w; acc[5] += h1.y * w; acc[6] += h1.z * w; acc[7] += h1.w * w;
  }
#pragma unroll
  for (int i = 0; i < 8; ++i)
    partials[((size_t)(path * 8 + esl) * NB + bg * 8 + i) * ND + d] = acc[i];
}

// ============ D5: epi: out = A*e0 + (sum partials + coef*bias) ===============
// 256 blocks: path(2) x b(32) x dchunk(4); 256 thr.
__global__ __launch_bounds__(256) void epi_kernel(
    const float* __restrict__ partials, const float* __restrict__ bv,
    const float* __restrict__ bk, const float* __restrict__ eV0,
    const float* __restrict__ eK0, const float* __restrict__ Abuf,
    const float* __restrict__ csum, const float* __restrict__ wsum,
    float* __restrict__ outV, float* __restrict__ outK) {
  int bid = blockIdx.x;
  int path = bid >> 7;
  int id2 = bid & 127;
  int b = id2 >> 2, dc = id2 & 3;
  int d = dc * 256 + threadIdx.x;
  float s = 0.f;
#pragma unroll
  for (int sl = 0; sl < 8; ++sl)
    s += partials[((size_t)(path * 8 + sl) * NB + b) * ND + d];
  const float* bias = path ? bk : bv;
  const float* coef = path ? wsum : csum;
  const float* e0p = path ? eK0 : eV0;
  float* out = path ? outK : outV;
  s += coef[b] * bias[d];
  float A = Abuf[b];
#pragma unroll
  for (int r = 0; r < NR; ++r) {
    size_t idx = ((size_t)(b * NR + r)) * ND + d;
    out[idx] = A * e0p[idx] + s;
  }
}

extern "C" void kernel_launch(void* const* d_in, const int* in_sizes, int n_in,
                              void* d_out, int out_size, void* d_ws, size_t ws_size,
                              hipStream_t stream) {
  (void)in_sizes; (void)n_in; (void)out_size; (void)ws_size;
  const float* x_all    = (const float*)d_in[0];
  const float* h_all    = (const float*)d_in[1];
  const float* surprise = (const float*)d_in[2];
  const void*  mask     = d_in[3];
  const float* pmK      = (const float*)d_in[4];
  const float* pmV      = (const float*)d_in[5];
  const float* pma      = (const float*)d_in[6];
  const float* eK0      = (const float*)d_in[7];
  const float* eV0      = (const float*)d_in[8];
  const float* Wk       = (const float*)d_in[9];
  const float* bk       = (const float*)d_in[10];
  const float* Wv       = (const float*)d_in[11];
  const float* bv       = (const float*)d_in[12];

  float* y    = (float*)d_out;
  float* outK = y + (size_t)NB * NP * ND;
  float* outV = outK + (size_t)NB * NR * ND;

  char* w = (char*)d_ws;
  float* c        = (float*)w; w += NB * NP * 4;               // 16 KB
  float* Abuf     = (float*)w; w += 256;
  float* csum     = (float*)w; w += 256;
  float* wsum     = (float*)w; w += 256;
  float* hbar     = (float*)w; w += NB * ND * 4;               // 128 KB
  float* xbar     = (float*)w; w += NB * ND * 4;               // 128 KB
  float* norms2p  = (float*)w; w += (size_t)16 * NB * NP * 4;  // 256 KB
  float* xnorm    = (float*)w; w += NB * NP * 4;               // 16 KB
  float* partials = (float*)w; w += (size_t)16 * NB * ND * 4;  // 2 MB
  ushort_t* WkT   = (ushort_t*)w; w += (size_t)ND * ND * 2;    // 2 MB
  ushort_t* pmKb  = (ushort_t*)w; w += (size_t)NB * NR * ND * 2;  // 1 MB
  ushort_t* Xb    = (ushort_t*)w; w += (size_t)NB * NP * ND * 2;  // 8 MB

  prep_kernel<<<NB + NB * NP + 256 + 256, 256, 0, stream>>>(
      surprise, mask, x_all, Wk, pmK, c, Abuf, csum, Xb, xnorm, WkT, pmKb);
  main_kernel<<<512 + 512, 256, 0, stream>>>(Xb, WkT, bk, norms2p, h_all, c, hbar);
  mid_kernel<<<256 + 256, 256, 0, stream>>>(Xb, norms2p, c, xbar, wsum, pmKb,
                                            pmV, pma, xnorm, y);
  vkbar_kernel<<<256, 256, 0, stream>>>(hbar, xbar, Wv, Wk, partials);
  epi_kernel<<<256, 256, 0, stream>>>(partials, bv, bk, eV0, eK0, Abuf, csum,
                                      wsum, outV, outK);
}